// Round 1
// baseline (2047.309 us; speedup 1.0000x reference)
//
#include <hip/hip_runtime.h>
#include <hip/hip_bf16.h>

#define N_NODES 100000
#define N_EDGES 1600000
#define E_TOT   (N_EDGES + N_NODES)   // edges + self-loops = 1,700,000
#define NEG_SLOPE 0.2f

// ---------------------------------------------------------------------------
// Edge dtype probe: reference uses int64 edge_index, harness doc says int32.
// If data is int64, every 64-bit value is a node id < 100000. If data is
// int32, the 64-bit view combines two node ids -> almost surely >= 2^32.
// ---------------------------------------------------------------------------
__device__ __forceinline__ bool edges_are_i64(const void* p) {
    const unsigned long long* q = (const unsigned long long*)p;
    bool ok = true;
#pragma unroll
    for (int i = 0; i < 8; i++) {
        if (q[i] >= (unsigned long long)N_NODES) ok = false;
    }
    return ok;
}

__global__ void convert_edges(const void* __restrict__ ei, int* __restrict__ s32,
                              int* __restrict__ d32) {
    int j = blockIdx.x * blockDim.x + threadIdx.x;
    if (j >= N_EDGES) return;
    if (edges_are_i64(ei)) {
        const long long* q = (const long long*)ei;
        s32[j] = (int)q[j];
        d32[j] = (int)q[N_EDGES + j];
    } else {
        const int* q = (const int*)ei;
        s32[j] = q[j];
        d32[j] = q[N_EDGES + j];
    }
}

// ---------------------------------------------------------------------------
// GEMM: H[n x M] = X[n x K] @ W[K x M]; 16 rows per 256-thread block.
// K = 128 always here. M in {128, 64}.
// ---------------------------------------------------------------------------
template <int K, int M>
__global__ __launch_bounds__(256) void gemm16(const float* __restrict__ X,
                                              const float* __restrict__ W,
                                              float* __restrict__ H, int n) {
    constexpr int RPT = 16 / (256 / M);  // rows per thread
    __shared__ float xs[16][K];
    const int row0 = blockIdx.x * 16;
    const int t = threadIdx.x;

    // stage 16 rows of X into LDS (float4)
    for (int i = t; i < 16 * K / 4; i += 256) {
        int r = i / (K / 4);
        int c = i % (K / 4);
        float4 v = make_float4(0.f, 0.f, 0.f, 0.f);
        if (row0 + r < n) v = ((const float4*)(X + (size_t)(row0 + r) * K))[c];
        ((float4*)xs[r])[c] = v;
    }
    __syncthreads();

    const int col = t % M;
    const int rg = t / M;  // row group
    float acc[RPT];
#pragma unroll
    for (int i = 0; i < RPT; i++) acc[i] = 0.f;

    for (int k = 0; k < K; k++) {
        float w = W[k * M + col];
#pragma unroll
        for (int i = 0; i < RPT; i++) acc[i] = fmaf(xs[rg * RPT + i][k], w, acc[i]);
    }
#pragma unroll
    for (int i = 0; i < RPT; i++) {
        int r = row0 + rg * RPT + i;
        if (r < n) H[(size_t)r * M + col] = acc[i];
    }
}

// ---------------------------------------------------------------------------
// Per-node attention half-scores: a_src[n,h] = sum_c H[n,h,c]*att_src[h,c]
// ---------------------------------------------------------------------------
template <int HEADS, int CH>
__global__ void att_scores(const float* __restrict__ H, const float* __restrict__ att_s,
                           const float* __restrict__ att_d, float* __restrict__ a_s,
                           float* __restrict__ a_d, int n) {
    int idx = blockIdx.x * blockDim.x + threadIdx.x;
    if (idx >= n * HEADS) return;
    int node = idx / HEADS;
    int h = idx - node * HEADS;
    const float* hp = H + (size_t)node * (HEADS * CH) + h * CH;
    float s = 0.f, d = 0.f;
#pragma unroll
    for (int c = 0; c < CH; c++) {
        float v = hp[c];
        s = fmaf(v, att_s[h * CH + c], s);
        d = fmaf(v, att_d[h * CH + c], d);
    }
    a_s[idx] = s;
    a_d[idx] = d;
}

// ---------------------------------------------------------------------------
// Softmax denominators per dst node (max-shift skipped: scores are O(1),
// softmax is shift-invariant, so exp(e)/sum(exp(e)) == reference exactly).
// ---------------------------------------------------------------------------
template <int HEADS>
__global__ void edge_denom(const int* __restrict__ src_arr, const int* __restrict__ dst_arr,
                           const float* __restrict__ a_s, const float* __restrict__ a_d,
                           float* __restrict__ denom) {
    int j = blockIdx.x * blockDim.x + threadIdx.x;
    if (j >= E_TOT) return;
    int s, d;
    if (j < N_EDGES) { s = src_arr[j]; d = dst_arr[j]; }
    else             { s = d = j - N_EDGES; }
#pragma unroll
    for (int h = 0; h < HEADS; h++) {
        float e = a_s[(size_t)s * HEADS + h] + a_d[(size_t)d * HEADS + h];
        e = e > 0.f ? e : NEG_SLOPE * e;
        atomicAdd(&denom[(size_t)d * HEADS + h], __expf(e));
    }
}

// ---------------------------------------------------------------------------
// Aggregation: OUT[dst, c] += H[src, c] * alpha(edge, head(c))
// One thread per (edge, channel).
// ---------------------------------------------------------------------------
template <int HEADS, int CH>
__global__ void edge_aggr(const int* __restrict__ src_arr, const int* __restrict__ dst_arr,
                          const float* __restrict__ a_s, const float* __restrict__ a_d,
                          const float* __restrict__ denom, const float* __restrict__ H,
                          float* __restrict__ OUT) {
    constexpr int F = HEADS * CH;
    long long gid = (long long)blockIdx.x * blockDim.x + threadIdx.x;
    if (gid >= (long long)E_TOT * F) return;
    int j = (int)(gid / F);
    int c = (int)(gid - (long long)j * F);
    int h = c / CH;
    int s, d;
    if (j < N_EDGES) { s = src_arr[j]; d = dst_arr[j]; }
    else             { s = d = j - N_EDGES; }
    float e = a_s[(size_t)s * HEADS + h] + a_d[(size_t)d * HEADS + h];
    e = e > 0.f ? e : NEG_SLOPE * e;
    float alpha = __expf(e) / (denom[(size_t)d * HEADS + h] + 1e-16f);
    atomicAdd(&OUT[(size_t)d * F + c], H[(size_t)s * F + c] * alpha);
}

// ---------------------------------------------------------------------------
// out1 = relu(out1 + bias) over n x 128, float4-vectorized
// ---------------------------------------------------------------------------
__global__ void relu_bias_k(float4* __restrict__ buf, const float* __restrict__ bias,
                            long long n4) {
    long long i = (long long)blockIdx.x * blockDim.x + threadIdx.x;
    if (i >= n4) return;
    int c4 = (int)(i & 31);  // 128/4 = 32 float4 per row
    float4 v = buf[i];
    const float4 b = ((const float4*)bias)[c4];
    v.x = fmaxf(v.x + b.x, 0.f);
    v.y = fmaxf(v.y + b.y, 0.f);
    v.z = fmaxf(v.z + b.z, 0.f);
    v.w = fmaxf(v.w + b.w, 0.f);
    buf[i] = v;
}

// ---------------------------------------------------------------------------
// log_softmax over rows of 64; one wave per row, 4 rows per block.
// ---------------------------------------------------------------------------
__global__ __launch_bounds__(256) void logsoftmax_k(const float* __restrict__ Z,
                                                    const float* __restrict__ bias,
                                                    float* __restrict__ OUT, int n) {
    int lane = threadIdx.x & 63;
    int wv = threadIdx.x >> 6;
    int r = blockIdx.x * 4 + wv;
    if (r >= n) return;
    float z = Z[(size_t)r * 64 + lane] + bias[lane];
    float m = z;
#pragma unroll
    for (int o = 32; o > 0; o >>= 1) m = fmaxf(m, __shfl_xor(m, o, 64));
    float p = __expf(z - m);
    float ssum = p;
#pragma unroll
    for (int o = 32; o > 0; o >>= 1) ssum += __shfl_xor(ssum, o, 64);
    OUT[(size_t)r * 64 + lane] = z - m - logf(ssum);
}

// ---------------------------------------------------------------------------
extern "C" void kernel_launch(void* const* d_in, const int* in_sizes, int n_in,
                              void* d_out, int out_size, void* d_ws, size_t ws_size,
                              hipStream_t stream) {
    const float* x   = (const float*)d_in[0];
    const void*  ei  = d_in[1];
    const float* W1  = (const float*)d_in[2];
    const float* as1 = (const float*)d_in[3];
    const float* ad1 = (const float*)d_in[4];
    const float* b1  = (const float*)d_in[5];
    const float* W2  = (const float*)d_in[6];
    const float* as2 = (const float*)d_in[7];
    const float* ad2 = (const float*)d_in[8];
    const float* b2  = (const float*)d_in[9];
    float* out = (float*)d_out;
    float* ws  = (float*)d_ws;

    // workspace layout (floats)
    float* h1   = ws;                                   // N*128 (reused: h2 first half, out2 second half)
    float* out1 = ws + (size_t)N_NODES * 128;           // N*128
    float* a_s  = out1 + (size_t)N_NODES * 128;         // N*8
    float* a_d  = a_s + (size_t)N_NODES * 8;            // N*8
    float* den  = a_d + (size_t)N_NODES * 8;            // N*8
    int*   s32  = (int*)(den + (size_t)N_NODES * 8);    // E ints
    int*   d32  = s32 + N_EDGES;                        // E ints
    float* h2   = h1;                                   // N*64
    float* out2 = h1 + (size_t)N_NODES * 64;            // N*64

    // --- edge conversion (handles int64 or int32 input) ---
    convert_edges<<<(N_EDGES + 255) / 256, 256, 0, stream>>>(ei, s32, d32);

    // --- layer 1 ---
    hipMemsetAsync(out1, 0, (size_t)N_NODES * 128 * sizeof(float), stream);
    hipMemsetAsync(den, 0, (size_t)N_NODES * 8 * sizeof(float), stream);

    gemm16<128, 128><<<(N_NODES + 15) / 16, 256, 0, stream>>>(x, W1, h1, N_NODES);
    att_scores<8, 16><<<(N_NODES * 8 + 255) / 256, 256, 0, stream>>>(h1, as1, ad1, a_s, a_d, N_NODES);
    edge_denom<8><<<(E_TOT + 255) / 256, 256, 0, stream>>>(s32, d32, a_s, a_d, den);
    edge_aggr<8, 16><<<(int)(((long long)E_TOT * 128 + 255) / 256), 256, 0, stream>>>(
        s32, d32, a_s, a_d, den, h1, out1);
    relu_bias_k<<<(int)(((long long)N_NODES * 32 + 255) / 256), 256, 0, stream>>>(
        (float4*)out1, b1, (long long)N_NODES * 32);

    // --- layer 2 ---
    gemm16<128, 64><<<(N_NODES + 15) / 16, 256, 0, stream>>>(out1, W2, h2, N_NODES);
    att_scores<1, 64><<<(N_NODES + 255) / 256, 256, 0, stream>>>(h2, as2, ad2, a_s, a_d, N_NODES);
    hipMemsetAsync(out2, 0, (size_t)N_NODES * 64 * sizeof(float), stream);
    hipMemsetAsync(den, 0, (size_t)N_NODES * sizeof(float), stream);
    edge_denom<1><<<(E_TOT + 255) / 256, 256, 0, stream>>>(s32, d32, a_s, a_d, den);
    edge_aggr<1, 64><<<(int)(((long long)E_TOT * 64 + 255) / 256), 256, 0, stream>>>(
        s32, d32, a_s, a_d, den, h2, out2);

    // --- log_softmax ---
    logsoftmax_k<<<(N_NODES + 3) / 4, 256, 0, stream>>>(out2, b2, out, N_NODES);
}

// Round 2
// 676.672 us; speedup vs baseline: 3.0256x; 3.0256x over previous
//
#include <hip/hip_runtime.h>
#include <hip/hip_bf16.h>

#define N_NODES 100000
#define N_EDGES 1600000
#define NEG_SLOPE 0.2f

#define SCAN_ITEMS 4
#define SCAN_BLK 256
#define SCAN_CHUNK (SCAN_BLK * SCAN_ITEMS)                      // 1024
#define SCAN_NBLK ((N_NODES + SCAN_CHUNK - 1) / SCAN_CHUNK)     // 98

// ---------------------------------------------------------------------------
// Edge dtype probe: reference uses int64 edge_index; harness may hand int32.
// int64 data: every 64-bit word is a node id < 100000. int32 data: a 64-bit
// view mixes two ids -> almost surely >= 2^32. Uniform loads, L1-cached.
// ---------------------------------------------------------------------------
__device__ __forceinline__ bool edges_are_i64(const void* p) {
    const unsigned long long* q = (const unsigned long long*)p;
    bool ok = true;
#pragma unroll
    for (int i = 0; i < 8; i++)
        if (q[i] >= (unsigned long long)N_NODES) ok = false;
    return ok;
}

__device__ __forceinline__ int edge_src(const void* ei, int j, bool i64) {
    return i64 ? (int)((const long long*)ei)[j] : ((const int*)ei)[j];
}
__device__ __forceinline__ int edge_dst(const void* ei, int j, bool i64) {
    return i64 ? (int)((const long long*)ei)[N_EDGES + j] : ((const int*)ei)[N_EDGES + j];
}

// ---------------------------------------------------------------------------
// CSR build: histogram -> block scan -> scatter
// ---------------------------------------------------------------------------
__global__ void hist_k(const void* __restrict__ ei, int* __restrict__ deg) {
    int j = blockIdx.x * blockDim.x + threadIdx.x;
    if (j >= N_EDGES) return;
    bool i64 = edges_are_i64(ei);
    atomicAdd(&deg[edge_dst(ei, j, i64)], 1);
}

__global__ __launch_bounds__(SCAN_BLK) void scan1_k(const int* __restrict__ deg,
                                                    int* __restrict__ rp,
                                                    int* __restrict__ bsum) {
    __shared__ int lds[SCAN_BLK];
    int t = threadIdx.x, b = blockIdx.x;
    int base = b * SCAN_CHUNK + t * SCAN_ITEMS;
    int v[SCAN_ITEMS];
    int s = 0;
#pragma unroll
    for (int i = 0; i < SCAN_ITEMS; i++) {
        v[i] = (base + i < N_NODES) ? deg[base + i] : 0;
        s += v[i];
    }
    lds[t] = s;
    __syncthreads();
    for (int o = 1; o < SCAN_BLK; o <<= 1) {
        int x = (t >= o) ? lds[t - o] : 0;
        __syncthreads();
        lds[t] += x;
        __syncthreads();
    }
    if (t == SCAN_BLK - 1) bsum[b] = lds[t];
    int run = lds[t] - s;  // exclusive prefix of this thread
#pragma unroll
    for (int i = 0; i < SCAN_ITEMS; i++) {
        if (base + i < N_NODES) rp[base + i] = run;
        run += v[i];
    }
}

__global__ __launch_bounds__(128) void scan2_k(int* __restrict__ bsum) {
    __shared__ int lds[128];
    int t = threadIdx.x;
    int v = (t < SCAN_NBLK) ? bsum[t] : 0;
    lds[t] = v;
    __syncthreads();
    for (int o = 1; o < 128; o <<= 1) {
        int x = (t >= o) ? lds[t - o] : 0;
        __syncthreads();
        lds[t] += x;
        __syncthreads();
    }
    if (t < SCAN_NBLK) bsum[t] = lds[t] - v;  // exclusive
}

__global__ void scan3_k(int* __restrict__ rp, const int* __restrict__ bsum) {
    int i = blockIdx.x * blockDim.x + threadIdx.x;
    if (i < N_NODES) rp[i] += bsum[i / SCAN_CHUNK];
    if (i == 0) rp[N_NODES] = N_EDGES;
}

__global__ void scatter_k(const void* __restrict__ ei, int* __restrict__ cursor,
                          int* __restrict__ csrc) {
    int j = blockIdx.x * blockDim.x + threadIdx.x;
    if (j >= N_EDGES) return;
    bool i64 = edges_are_i64(ei);
    int s = edge_src(ei, j, i64);
    int d = edge_dst(ei, j, i64);
    int pos = atomicAdd(&cursor[d], 1);
    csrc[pos] = s;
}

// ---------------------------------------------------------------------------
// GEMM: H[n x M] = X[n x K] @ W[K x M]; 16 rows per 256-thread block.
// ---------------------------------------------------------------------------
template <int K, int M>
__global__ __launch_bounds__(256) void gemm16(const float* __restrict__ X,
                                              const float* __restrict__ W,
                                              float* __restrict__ H, int n) {
    constexpr int RPT = 16 / (256 / M);
    __shared__ float xs[16][K];
    const int row0 = blockIdx.x * 16;
    const int t = threadIdx.x;

    for (int i = t; i < 16 * K / 4; i += 256) {
        int r = i / (K / 4);
        int c = i % (K / 4);
        float4 v = make_float4(0.f, 0.f, 0.f, 0.f);
        if (row0 + r < n) v = ((const float4*)(X + (size_t)(row0 + r) * K))[c];
        ((float4*)xs[r])[c] = v;
    }
    __syncthreads();

    const int col = t % M;
    const int rg = t / M;
    float acc[RPT];
#pragma unroll
    for (int i = 0; i < RPT; i++) acc[i] = 0.f;
    for (int k = 0; k < K; k++) {
        float w = W[k * M + col];
#pragma unroll
        for (int i = 0; i < RPT; i++) acc[i] = fmaf(xs[rg * RPT + i][k], w, acc[i]);
    }
#pragma unroll
    for (int i = 0; i < RPT; i++) {
        int r = row0 + rg * RPT + i;
        if (r < n) H[(size_t)r * M + col] = acc[i];
    }
}

// ---------------------------------------------------------------------------
// Per-node attention half-scores
// ---------------------------------------------------------------------------
template <int HEADS, int CH>
__global__ void att_scores(const float* __restrict__ H, const float* __restrict__ att_s,
                           const float* __restrict__ att_d, float* __restrict__ a_s,
                           float* __restrict__ a_d, int n) {
    int idx = blockIdx.x * blockDim.x + threadIdx.x;
    if (idx >= n * HEADS) return;
    int node = idx / HEADS;
    int h = idx - node * HEADS;
    const float* hp = H + (size_t)node * (HEADS * CH) + h * CH;
    float s = 0.f, d = 0.f;
#pragma unroll
    for (int c = 0; c < CH; c++) {
        float v = hp[c];
        s = fmaf(v, att_s[h * CH + c], s);
        d = fmaf(v, att_d[h * CH + c], d);
    }
    a_s[idx] = s;
    a_d[idx] = d;
}

// ---------------------------------------------------------------------------
// Layer 1 fused aggregation: one wave per dst node; num/den in registers.
// Epilogue: +bias, ReLU. lane -> float2 channels [2*lane, 2*lane+1],
// head = lane>>3 (16 ch per head). Self-loop handled inline.
// ---------------------------------------------------------------------------
__global__ __launch_bounds__(256) void aggr1_k(const int* __restrict__ rp,
                                               const int* __restrict__ csrc,
                                               const float* __restrict__ a_s,
                                               const float* __restrict__ a_d,
                                               const float* __restrict__ h,
                                               const float* __restrict__ bias,
                                               float* __restrict__ out) {
    int lane = threadIdx.x & 63;
    int d = blockIdx.x * 4 + (threadIdx.x >> 6);
    if (d >= N_NODES) return;
    int head = lane >> 3;

    float ed = a_d[d * 8 + head];
    // self loop
    float e = a_s[d * 8 + head] + ed;
    e = e > 0.f ? e : NEG_SLOPE * e;
    float w = __expf(e);
    float2 hv = ((const float2*)(h + (size_t)d * 128))[lane];
    float den = w;
    float nx = w * hv.x, ny = w * hv.y;

    int beg = rp[d], end = rp[d + 1];
    for (int i = beg; i < end; i++) {
        int s = csrc[i];
        float es = a_s[s * 8 + head] + ed;
        es = es > 0.f ? es : NEG_SLOPE * es;
        float we = __expf(es);
        float2 v = ((const float2*)(h + (size_t)s * 128))[lane];
        den += we;
        nx = fmaf(we, v.x, nx);
        ny = fmaf(we, v.y, ny);
    }
    float inv = 1.f / (den + 1e-16f);
    float2 b = ((const float2*)bias)[lane];
    float2 r;
    r.x = fmaxf(fmaf(nx, inv, b.x), 0.f);
    r.y = fmaxf(fmaf(ny, inv, b.y), 0.f);
    ((float2*)(out + (size_t)d * 128))[lane] = r;
}

// ---------------------------------------------------------------------------
// Layer 2 fused aggregation + bias + log_softmax: one wave per node,
// lane = channel (64). Single head.
// ---------------------------------------------------------------------------
__global__ __launch_bounds__(256) void aggr2_k(const int* __restrict__ rp,
                                               const int* __restrict__ csrc,
                                               const float* __restrict__ a_s,
                                               const float* __restrict__ a_d,
                                               const float* __restrict__ h,
                                               const float* __restrict__ bias,
                                               float* __restrict__ out) {
    int lane = threadIdx.x & 63;
    int d = blockIdx.x * 4 + (threadIdx.x >> 6);
    if (d >= N_NODES) return;

    float ed = a_d[d];
    float e = a_s[d] + ed;
    e = e > 0.f ? e : NEG_SLOPE * e;
    float w = __expf(e);
    float den = w;
    float num = w * h[(size_t)d * 64 + lane];

    int beg = rp[d], end = rp[d + 1];
    for (int i = beg; i < end; i++) {
        int s = csrc[i];
        float es = a_s[s] + ed;
        es = es > 0.f ? es : NEG_SLOPE * es;
        float we = __expf(es);
        den += we;
        num = fmaf(we, h[(size_t)s * 64 + lane], num);
    }
    float z = num / (den + 1e-16f) + bias[lane];

    float m = z;
#pragma unroll
    for (int o = 32; o > 0; o >>= 1) m = fmaxf(m, __shfl_xor(m, o, 64));
    float p = __expf(z - m);
    float ssum = p;
#pragma unroll
    for (int o = 32; o > 0; o >>= 1) ssum += __shfl_xor(ssum, o, 64);
    out[(size_t)d * 64 + lane] = z - m - logf(ssum);
}

// ---------------------------------------------------------------------------
extern "C" void kernel_launch(void* const* d_in, const int* in_sizes, int n_in,
                              void* d_out, int out_size, void* d_ws, size_t ws_size,
                              hipStream_t stream) {
    const float* x   = (const float*)d_in[0];
    const void*  ei  = d_in[1];
    const float* W1  = (const float*)d_in[2];
    const float* as1 = (const float*)d_in[3];
    const float* ad1 = (const float*)d_in[4];
    const float* b1  = (const float*)d_in[5];
    const float* W2  = (const float*)d_in[6];
    const float* as2 = (const float*)d_in[7];
    const float* ad2 = (const float*)d_in[8];
    const float* b2  = (const float*)d_in[9];
    float* out = (float*)d_out;
    float* ws  = (float*)d_ws;

    // workspace layout
    float* h1   = ws;                                   // N*128 (reused as h2: N*64)
    float* out1 = h1 + (size_t)N_NODES * 128;           // N*128
    float* a_s  = out1 + (size_t)N_NODES * 128;         // N*8
    float* a_d  = a_s + (size_t)N_NODES * 8;            // N*8
    int*   rp   = (int*)(a_d + (size_t)N_NODES * 8);    // N+1
    int*   deg  = rp + (N_NODES + 1);                   // N (reused as scatter cursor)
    int*   bsum = deg + N_NODES;                        // SCAN_NBLK
    int*   csrc = bsum + ((SCAN_NBLK + 63) & ~63);      // E
    float* h2   = h1;

    // --- CSR build (by dst) ---
    hipMemsetAsync(deg, 0, (size_t)N_NODES * sizeof(int), stream);
    hist_k<<<(N_EDGES + 255) / 256, 256, 0, stream>>>(ei, deg);
    scan1_k<<<SCAN_NBLK, SCAN_BLK, 0, stream>>>(deg, rp, bsum);
    scan2_k<<<1, 128, 0, stream>>>(bsum);
    scan3_k<<<(N_NODES + 255) / 256, 256, 0, stream>>>(rp, bsum);
    hipMemcpyAsync(deg, rp, (size_t)N_NODES * sizeof(int),
                   hipMemcpyDeviceToDevice, stream);  // cursor = row_ptr
    scatter_k<<<(N_EDGES + 255) / 256, 256, 0, stream>>>(ei, deg, csrc);

    // --- layer 1 ---
    gemm16<128, 128><<<(N_NODES + 15) / 16, 256, 0, stream>>>(x, W1, h1, N_NODES);
    att_scores<8, 16><<<(N_NODES * 8 + 255) / 256, 256, 0, stream>>>(h1, as1, ad1, a_s, a_d, N_NODES);
    aggr1_k<<<(N_NODES + 3) / 4, 256, 0, stream>>>(rp, csrc, a_s, a_d, h1, b1, out1);

    // --- layer 2 (fused bias + log_softmax) ---
    gemm16<128, 64><<<(N_NODES + 15) / 16, 256, 0, stream>>>(out1, W2, h2, N_NODES);
    att_scores<1, 64><<<(N_NODES + 255) / 256, 256, 0, stream>>>(h2, as2, ad2, a_s, a_d, N_NODES);
    aggr2_k<<<(N_NODES + 3) / 4, 256, 0, stream>>>(rp, csrc, a_s, a_d, h2, b2, out);
}

// Round 3
// 473.864 us; speedup vs baseline: 4.3205x; 1.4280x over previous
//
#include <hip/hip_runtime.h>
#include <hip/hip_bf16.h>

#define N_NODES 100000
#define N_EDGES 1600000
#define NEG_SLOPE 0.2f

#define SCAN_ITEMS 4
#define SCAN_BLK 256
#define SCAN_CHUNK (SCAN_BLK * SCAN_ITEMS)                      // 1024
#define SCAN_NBLK ((N_NODES + SCAN_CHUNK - 1) / SCAN_CHUNK)     // 98

typedef _Float16 f16;
typedef _Float16 f16x8 __attribute__((ext_vector_type(8)));
typedef _Float16 f16x2 __attribute__((ext_vector_type(2)));
typedef float f32x4 __attribute__((ext_vector_type(4)));

// ---------------------------------------------------------------------------
// Edge dtype probe (int64 reference vs possible int32 delivery)
// ---------------------------------------------------------------------------
__device__ __forceinline__ bool edges_are_i64(const void* p) {
    const unsigned long long* q = (const unsigned long long*)p;
    bool ok = true;
#pragma unroll
    for (int i = 0; i < 8; i++)
        if (q[i] >= (unsigned long long)N_NODES) ok = false;
    return ok;
}
__device__ __forceinline__ int edge_src(const void* ei, int j, bool i64) {
    return i64 ? (int)((const long long*)ei)[j] : ((const int*)ei)[j];
}
__device__ __forceinline__ int edge_dst(const void* ei, int j, bool i64) {
    return i64 ? (int)((const long long*)ei)[N_EDGES + j] : ((const int*)ei)[N_EDGES + j];
}

// ---------------------------------------------------------------------------
// CSR build: histogram -> block scan -> scatter
// ---------------------------------------------------------------------------
__global__ void hist_k(const void* __restrict__ ei, int* __restrict__ deg) {
    int j = blockIdx.x * blockDim.x + threadIdx.x;
    if (j >= N_EDGES) return;
    bool i64 = edges_are_i64(ei);
    atomicAdd(&deg[edge_dst(ei, j, i64)], 1);
}

__global__ __launch_bounds__(SCAN_BLK) void scan1_k(const int* __restrict__ deg,
                                                    int* __restrict__ rp,
                                                    int* __restrict__ bsum) {
    __shared__ int lds[SCAN_BLK];
    int t = threadIdx.x, b = blockIdx.x;
    int base = b * SCAN_CHUNK + t * SCAN_ITEMS;
    int v[SCAN_ITEMS];
    int s = 0;
#pragma unroll
    for (int i = 0; i < SCAN_ITEMS; i++) {
        v[i] = (base + i < N_NODES) ? deg[base + i] : 0;
        s += v[i];
    }
    lds[t] = s;
    __syncthreads();
    for (int o = 1; o < SCAN_BLK; o <<= 1) {
        int x = (t >= o) ? lds[t - o] : 0;
        __syncthreads();
        lds[t] += x;
        __syncthreads();
    }
    if (t == SCAN_BLK - 1) bsum[b] = lds[t];
    int run = lds[t] - s;
#pragma unroll
    for (int i = 0; i < SCAN_ITEMS; i++) {
        if (base + i < N_NODES) rp[base + i] = run;
        run += v[i];
    }
}

__global__ __launch_bounds__(128) void scan2_k(int* __restrict__ bsum) {
    __shared__ int lds[128];
    int t = threadIdx.x;
    int v = (t < SCAN_NBLK) ? bsum[t] : 0;
    lds[t] = v;
    __syncthreads();
    for (int o = 1; o < 128; o <<= 1) {
        int x = (t >= o) ? lds[t - o] : 0;
        __syncthreads();
        lds[t] += x;
        __syncthreads();
    }
    if (t < SCAN_NBLK) bsum[t] = lds[t] - v;
}

__global__ void scan3_k(int* __restrict__ rp, const int* __restrict__ bsum) {
    int i = blockIdx.x * blockDim.x + threadIdx.x;
    if (i < N_NODES) rp[i] += bsum[i / SCAN_CHUNK];
    if (i == 0) rp[N_NODES] = N_EDGES;
}

__global__ void scatter_k(const void* __restrict__ ei, int* __restrict__ cursor,
                          int* __restrict__ csrc) {
    int j = blockIdx.x * blockDim.x + threadIdx.x;
    if (j >= N_EDGES) return;
    bool i64 = edges_are_i64(ei);
    int s = edge_src(ei, j, i64);
    int d = edge_dst(ei, j, i64);
    int pos = atomicAdd(&cursor[d], 1);
    csrc[pos] = s;
}

// ---------------------------------------------------------------------------
// f32 -> f16 conversion, 8 elems/thread
// ---------------------------------------------------------------------------
__global__ void cvt_f16_k(const float* __restrict__ in, f16* __restrict__ outp,
                          long long n8) {
    long long i = (long long)blockIdx.x * blockDim.x + threadIdx.x;
    if (i >= n8) return;
    const float4* p = (const float4*)(in + i * 8);
    float4 a = p[0], b = p[1];
    f16x8 v;
    v[0] = (f16)a.x; v[1] = (f16)a.y; v[2] = (f16)a.z; v[3] = (f16)a.w;
    v[4] = (f16)b.x; v[5] = (f16)b.y; v[6] = (f16)b.z; v[7] = (f16)b.w;
    ((f16x8*)outp)[i] = v;
}

// ---------------------------------------------------------------------------
// Pre-shuffle W[K=128 x M=NCT*16] into MFMA B-fragment order:
// wf[(ks*NCT+ct)*64 + lane][j] = W[ks*32 + 8*(lane>>4) + j][ct*16 + (lane&15)]
// ---------------------------------------------------------------------------
template <int NCT>
__global__ void cvt_wfrag_k(const float* __restrict__ W, f16* __restrict__ wf) {
    int idx = blockIdx.x * blockDim.x + threadIdx.x;
    if (idx >= 4 * NCT * 512) return;
    int j = idx & 7;
    int lane = (idx >> 3) & 63;
    int ct = (idx >> 9) % NCT;
    int ks = (idx >> 9) / NCT;
    int k = ks * 32 + 8 * (lane >> 4) + j;
    int col = ct * 16 + (lane & 15);
    wf[idx] = (f16)W[k * (NCT * 16) + col];
}

// ---------------------------------------------------------------------------
// MFMA GEMM: H[n x NCT*16] = A[n x 128] @ W. 4 waves x 16 rows per block.
// A-fragment straight from global (lane: row=l&15, k=8*(l>>4)+j contiguous);
// B pre-shuffled; C/D mapping col=lane&15, row=(lane>>4)*4+reg (m89-verified).
// ---------------------------------------------------------------------------
template <int NCT>
__global__ __launch_bounds__(256) void gemm_mfma(const f16* __restrict__ A,
                                                 const f16* __restrict__ wf,
                                                 f16* __restrict__ H, int n) {
    int lane = threadIdx.x & 63;
    int row0 = blockIdx.x * 64 + (threadIdx.x >> 6) * 16;
    int m = lane & 15, g = lane >> 4;
    f32x4 acc[NCT];
#pragma unroll
    for (int ct = 0; ct < NCT; ct++) acc[ct] = (f32x4){0.f, 0.f, 0.f, 0.f};

    int ar = row0 + m;
    if (ar >= n) ar = 0;
    const f16x8* ap = (const f16x8*)(A + (size_t)ar * 128 + g * 8);
    const f16x8* bp = (const f16x8*)wf;
#pragma unroll
    for (int ks = 0; ks < 4; ks++) {
        f16x8 af = ap[ks * 4];
#pragma unroll
        for (int ct = 0; ct < NCT; ct++) {
            f16x8 bf = bp[(ks * NCT + ct) * 64 + lane];
            acc[ct] = __builtin_amdgcn_mfma_f32_16x16x32_f16(af, bf, acc[ct], 0, 0, 0);
        }
    }
#pragma unroll
    for (int ct = 0; ct < NCT; ct++)
#pragma unroll
        for (int r = 0; r < 4; r++) {
            int orow = row0 + g * 4 + r;
            if (orow < n) H[(size_t)orow * (NCT * 16) + ct * 16 + m] = (f16)acc[ct][r];
        }
}

// ---------------------------------------------------------------------------
// Per-node attention half-scores from f16 features
// ---------------------------------------------------------------------------
template <int HEADS, int CH>
__global__ void att_scores(const f16* __restrict__ H, const float* __restrict__ att_s,
                           const float* __restrict__ att_d, float* __restrict__ a_s,
                           float* __restrict__ a_d, int n) {
    int idx = blockIdx.x * blockDim.x + threadIdx.x;
    if (idx >= n * HEADS) return;
    int node = idx / HEADS;
    int h = idx - node * HEADS;
    const f16x8* hp = (const f16x8*)(H + (size_t)node * (HEADS * CH) + h * CH);
    float s = 0.f, d = 0.f;
#pragma unroll
    for (int c8 = 0; c8 < CH / 8; c8++) {
        f16x8 v = hp[c8];
#pragma unroll
        for (int j = 0; j < 8; j++) {
            float x = (float)v[j];
            s = fmaf(x, att_s[h * CH + c8 * 8 + j], s);
            d = fmaf(x, att_d[h * CH + c8 * 8 + j], d);
        }
    }
    a_s[idx] = s;
    a_d[idx] = d;
}

// ---------------------------------------------------------------------------
// Layer 1 fused aggregation (f16 gathers): one wave per dst node.
// lane -> channels [2l, 2l+1]; head = lane>>3. Epilogue: +bias, ReLU, f16 out.
// ---------------------------------------------------------------------------
__global__ __launch_bounds__(256) void aggr1_k(const int* __restrict__ rp,
                                               const int* __restrict__ csrc,
                                               const float* __restrict__ a_s,
                                               const float* __restrict__ a_d,
                                               const f16* __restrict__ h,
                                               const float* __restrict__ bias,
                                               f16* __restrict__ out) {
    int lane = threadIdx.x & 63;
    int d = blockIdx.x * 4 + (threadIdx.x >> 6);
    if (d >= N_NODES) return;
    int head = lane >> 3;
    const f16x2* hh = (const f16x2*)h;  // row stride 64 in f16x2 units

    float ed = a_d[d * 8 + head];
    float e = a_s[d * 8 + head] + ed;
    e = e > 0.f ? e : NEG_SLOPE * e;
    float w = __expf(e);
    f16x2 hv = hh[(size_t)d * 64 + lane];
    float den = w;
    float nx = w * (float)hv[0], ny = w * (float)hv[1];

    int beg = rp[d], end = rp[d + 1];
    int i = beg;
    for (; i + 2 <= end; i += 2) {
        int s0 = csrc[i], s1 = csrc[i + 1];
        float e0 = a_s[s0 * 8 + head] + ed;
        float e1 = a_s[s1 * 8 + head] + ed;
        e0 = e0 > 0.f ? e0 : NEG_SLOPE * e0;
        e1 = e1 > 0.f ? e1 : NEG_SLOPE * e1;
        float w0 = __expf(e0), w1 = __expf(e1);
        f16x2 v0 = hh[(size_t)s0 * 64 + lane];
        f16x2 v1 = hh[(size_t)s1 * 64 + lane];
        den += w0 + w1;
        nx = fmaf(w0, (float)v0[0], nx);
        ny = fmaf(w0, (float)v0[1], ny);
        nx = fmaf(w1, (float)v1[0], nx);
        ny = fmaf(w1, (float)v1[1], ny);
    }
    if (i < end) {
        int s0 = csrc[i];
        float e0 = a_s[s0 * 8 + head] + ed;
        e0 = e0 > 0.f ? e0 : NEG_SLOPE * e0;
        float w0 = __expf(e0);
        f16x2 v0 = hh[(size_t)s0 * 64 + lane];
        den += w0;
        nx = fmaf(w0, (float)v0[0], nx);
        ny = fmaf(w0, (float)v0[1], ny);
    }
    float inv = 1.f / (den + 1e-16f);
    float2 b = ((const float2*)bias)[lane];
    f16x2 r;
    r[0] = (f16)fmaxf(fmaf(nx, inv, b.x), 0.f);
    r[1] = (f16)fmaxf(fmaf(ny, inv, b.y), 0.f);
    ((f16x2*)out)[(size_t)d * 64 + lane] = r;
}

// ---------------------------------------------------------------------------
// Layer 2 fused aggregation + bias + log_softmax: one wave per node, lane=ch.
// ---------------------------------------------------------------------------
__global__ __launch_bounds__(256) void aggr2_k(const int* __restrict__ rp,
                                               const int* __restrict__ csrc,
                                               const float* __restrict__ a_s,
                                               const float* __restrict__ a_d,
                                               const f16* __restrict__ h,
                                               const float* __restrict__ bias,
                                               float* __restrict__ out) {
    int lane = threadIdx.x & 63;
    int d = blockIdx.x * 4 + (threadIdx.x >> 6);
    if (d >= N_NODES) return;

    float ed = a_d[d];
    float e = a_s[d] + ed;
    e = e > 0.f ? e : NEG_SLOPE * e;
    float w = __expf(e);
    float den = w;
    float num = w * (float)h[(size_t)d * 64 + lane];

    int beg = rp[d], end = rp[d + 1];
    int i = beg;
    for (; i + 2 <= end; i += 2) {
        int s0 = csrc[i], s1 = csrc[i + 1];
        float e0 = a_s[s0] + ed, e1 = a_s[s1] + ed;
        e0 = e0 > 0.f ? e0 : NEG_SLOPE * e0;
        e1 = e1 > 0.f ? e1 : NEG_SLOPE * e1;
        float w0 = __expf(e0), w1 = __expf(e1);
        float v0 = (float)h[(size_t)s0 * 64 + lane];
        float v1 = (float)h[(size_t)s1 * 64 + lane];
        den += w0 + w1;
        num = fmaf(w0, v0, num);
        num = fmaf(w1, v1, num);
    }
    if (i < end) {
        int s0 = csrc[i];
        float e0 = a_s[s0] + ed;
        e0 = e0 > 0.f ? e0 : NEG_SLOPE * e0;
        float w0 = __expf(e0);
        den += w0;
        num = fmaf(w0, (float)h[(size_t)s0 * 64 + lane], num);
    }
    float z = num / (den + 1e-16f) + bias[lane];

    float m = z;
#pragma unroll
    for (int o = 32; o > 0; o >>= 1) m = fmaxf(m, __shfl_xor(m, o, 64));
    float p = __expf(z - m);
    float ssum = p;
#pragma unroll
    for (int o = 32; o > 0; o >>= 1) ssum += __shfl_xor(ssum, o, 64);
    out[(size_t)d * 64 + lane] = z - m - logf(ssum);
}

// ---------------------------------------------------------------------------
extern "C" void kernel_launch(void* const* d_in, const int* in_sizes, int n_in,
                              void* d_out, int out_size, void* d_ws, size_t ws_size,
                              hipStream_t stream) {
    const float* x   = (const float*)d_in[0];
    const void*  ei  = d_in[1];
    const float* W1  = (const float*)d_in[2];
    const float* as1 = (const float*)d_in[3];
    const float* ad1 = (const float*)d_in[4];
    const float* b1  = (const float*)d_in[5];
    const float* W2  = (const float*)d_in[6];
    const float* as2 = (const float*)d_in[7];
    const float* ad2 = (const float*)d_in[8];
    const float* b2  = (const float*)d_in[9];
    float* out = (float*)d_out;

    // workspace layout
    f16*   xh   = (f16*)d_ws;                             // N*128 f16
    f16*   h1   = xh + (size_t)N_NODES * 128;             // N*128 f16 (reused as h2)
    f16*   out1 = h1 + (size_t)N_NODES * 128;             // N*128 f16
    f16*   w1f  = out1 + (size_t)N_NODES * 128;           // 16384 f16
    f16*   w2f  = w1f + 16384;                            // 8192 f16
    float* a_s  = (float*)(w2f + 8192);                   // N*8 f32
    float* a_d  = a_s + (size_t)N_NODES * 8;              // N*8 f32
    int*   rp   = (int*)(a_d + (size_t)N_NODES * 8);      // N+1
    int*   deg  = rp + (N_NODES + 64);                    // N (cursor reuse)
    int*   bsum = deg + N_NODES;                          // 128
    int*   csrc = bsum + 128;                             // E
    f16*   h2   = h1;

    // --- CSR build (by dst) ---
    hipMemsetAsync(deg, 0, (size_t)N_NODES * sizeof(int), stream);
    hist_k<<<(N_EDGES + 255) / 256, 256, 0, stream>>>(ei, deg);
    scan1_k<<<SCAN_NBLK, SCAN_BLK, 0, stream>>>(deg, rp, bsum);
    scan2_k<<<1, 128, 0, stream>>>(bsum);
    scan3_k<<<(N_NODES + 255) / 256, 256, 0, stream>>>(rp, bsum);
    hipMemcpyAsync(deg, rp, (size_t)N_NODES * sizeof(int),
                   hipMemcpyDeviceToDevice, stream);
    scatter_k<<<(N_EDGES + 255) / 256, 256, 0, stream>>>(ei, deg, csrc);

    // --- precision prep ---
    cvt_f16_k<<<(int)(((long long)N_NODES * 16 + 255) / 256), 256, 0, stream>>>(
        x, xh, (long long)N_NODES * 16);
    cvt_wfrag_k<8><<<(4 * 8 * 512 + 255) / 256, 256, 0, stream>>>(W1, w1f);
    cvt_wfrag_k<4><<<(4 * 4 * 512 + 255) / 256, 256, 0, stream>>>(W2, w2f);

    // --- layer 1 ---
    gemm_mfma<8><<<(N_NODES + 63) / 64, 256, 0, stream>>>(xh, w1f, h1, N_NODES);
    att_scores<8, 16><<<(N_NODES * 8 + 255) / 256, 256, 0, stream>>>(h1, as1, ad1, a_s, a_d, N_NODES);
    aggr1_k<<<(N_NODES + 3) / 4, 256, 0, stream>>>(rp, csrc, a_s, a_d, h1, b1, out1);

    // --- layer 2 (fused bias + log_softmax) ---
    gemm_mfma<4><<<(N_NODES + 63) / 64, 256, 0, stream>>>(out1, w2f, h2, N_NODES);
    att_scores<1, 64><<<(N_NODES + 255) / 256, 256, 0, stream>>>(h2, as2, ad2, a_s, a_d, N_NODES);
    aggr2_k<<<(N_NODES + 3) / 4, 256, 0, stream>>>(rp, csrc, a_s, a_d, h2, b2, out);
}

// Round 4
// 363.597 us; speedup vs baseline: 5.6307x; 1.3033x over previous
//
#include <hip/hip_runtime.h>
#include <hip/hip_bf16.h>

#define N_NODES 100000
#define N_EDGES 1600000
#define NEG_SLOPE 0.2f

#define SCAN_ITEMS 4
#define SCAN_BLK 256
#define SCAN_CHUNK (SCAN_BLK * SCAN_ITEMS)                      // 1024
#define SCAN_NBLK ((N_NODES + SCAN_CHUNK - 1) / SCAN_CHUNK)     // 98

typedef _Float16 f16;
typedef _Float16 f16x8 __attribute__((ext_vector_type(8)));
typedef _Float16 f16x2 __attribute__((ext_vector_type(2)));
typedef float f32x4 __attribute__((ext_vector_type(4)));

// ---------------------------------------------------------------------------
// Edge dtype probe (int64 reference vs possible int32 delivery)
// ---------------------------------------------------------------------------
__device__ __forceinline__ bool edges_are_i64(const void* p) {
    const unsigned long long* q = (const unsigned long long*)p;
    bool ok = true;
#pragma unroll
    for (int i = 0; i < 8; i++)
        if (q[i] >= (unsigned long long)N_NODES) ok = false;
    return ok;
}
__device__ __forceinline__ int edge_src(const void* ei, int j, bool i64) {
    return i64 ? (int)((const long long*)ei)[j] : ((const int*)ei)[j];
}
__device__ __forceinline__ int edge_dst(const void* ei, int j, bool i64) {
    return i64 ? (int)((const long long*)ei)[N_EDGES + j] : ((const int*)ei)[N_EDGES + j];
}

// ---------------------------------------------------------------------------
// CSR build pass A: degree histogram + per-edge rank (coalesced write).
// 4 edges per thread, grid-stride for atomic-latency ILP.
// ---------------------------------------------------------------------------
__global__ void rank_k(const void* __restrict__ ei, int* __restrict__ deg,
                       int* __restrict__ rank) {
    bool i64 = edges_are_i64(ei);
    int tid = blockIdx.x * blockDim.x + threadIdx.x;
    int stride = gridDim.x * blockDim.x;
#pragma unroll
    for (int u = 0; u < 4; u++) {
        int j = tid + u * stride;
        if (j < N_EDGES) rank[j] = atomicAdd(&deg[edge_dst(ei, j, i64)], 1);
    }
}

// ---------------------------------------------------------------------------
// CSR build pass B: placement. No atomics, no dependent ops after the store.
// ---------------------------------------------------------------------------
__global__ void scatter2_k(const void* __restrict__ ei, const int* __restrict__ rp,
                           const int* __restrict__ rank, int* __restrict__ csrc) {
    bool i64 = edges_are_i64(ei);
    int tid = blockIdx.x * blockDim.x + threadIdx.x;
    int stride = gridDim.x * blockDim.x;
#pragma unroll
    for (int u = 0; u < 4; u++) {
        int j = tid + u * stride;
        if (j < N_EDGES)
            csrc[rp[edge_dst(ei, j, i64)] + rank[j]] = edge_src(ei, j, i64);
    }
}

// ---------------------------------------------------------------------------
// Block scan over degrees -> row pointers
// ---------------------------------------------------------------------------
__global__ __launch_bounds__(SCAN_BLK) void scan1_k(const int* __restrict__ deg,
                                                    int* __restrict__ rp,
                                                    int* __restrict__ bsum) {
    __shared__ int lds[SCAN_BLK];
    int t = threadIdx.x, b = blockIdx.x;
    int base = b * SCAN_CHUNK + t * SCAN_ITEMS;
    int v[SCAN_ITEMS];
    int s = 0;
#pragma unroll
    for (int i = 0; i < SCAN_ITEMS; i++) {
        v[i] = (base + i < N_NODES) ? deg[base + i] : 0;
        s += v[i];
    }
    lds[t] = s;
    __syncthreads();
    for (int o = 1; o < SCAN_BLK; o <<= 1) {
        int x = (t >= o) ? lds[t - o] : 0;
        __syncthreads();
        lds[t] += x;
        __syncthreads();
    }
    if (t == SCAN_BLK - 1) bsum[b] = lds[t];
    int run = lds[t] - s;
#pragma unroll
    for (int i = 0; i < SCAN_ITEMS; i++) {
        if (base + i < N_NODES) rp[base + i] = run;
        run += v[i];
    }
}

__global__ __launch_bounds__(128) void scan2_k(int* __restrict__ bsum) {
    __shared__ int lds[128];
    int t = threadIdx.x;
    int v = (t < SCAN_NBLK) ? bsum[t] : 0;
    lds[t] = v;
    __syncthreads();
    for (int o = 1; o < 128; o <<= 1) {
        int x = (t >= o) ? lds[t - o] : 0;
        __syncthreads();
        lds[t] += x;
        __syncthreads();
    }
    if (t < SCAN_NBLK) bsum[t] = lds[t] - v;
}

__global__ void scan3_k(int* __restrict__ rp, const int* __restrict__ bsum) {
    int i = blockIdx.x * blockDim.x + threadIdx.x;
    if (i < N_NODES) rp[i] += bsum[i / SCAN_CHUNK];
    if (i == 0) rp[N_NODES] = N_EDGES;
}

// ---------------------------------------------------------------------------
// Pre-shuffle W[K=128 x M=NCT*16] into MFMA B-fragment order:
// wf[(ks*NCT+ct)*64 + lane][j] = W[ks*32 + 8*(lane>>4) + j][ct*16 + (lane&15)]
// ---------------------------------------------------------------------------
template <int NCT>
__global__ void cvt_wfrag_k(const float* __restrict__ W, f16* __restrict__ wf) {
    int idx = blockIdx.x * blockDim.x + threadIdx.x;
    if (idx >= 4 * NCT * 512) return;
    int j = idx & 7;
    int lane = (idx >> 3) & 63;
    int ct = (idx >> 9) % NCT;
    int ks = (idx >> 9) / NCT;
    int k = ks * 32 + 8 * (lane >> 4) + j;
    int col = ct * 16 + (lane & 15);
    wf[idx] = (f16)W[k * (NCT * 16) + col];
}

// ---------------------------------------------------------------------------
// MFMA GEMM: H[n x NCT*16] = A[n x 128] @ W. 4 waves x 16 rows per block.
// A may be f32 (converted in-flight) or f16. B pre-shuffled.
// C/D mapping col=lane&15, row=(lane>>4)*4+reg.
// ---------------------------------------------------------------------------
template <int NCT, typename AT>
__global__ __launch_bounds__(256) void gemm_mfma(const AT* __restrict__ A,
                                                 const f16* __restrict__ wf,
                                                 f16* __restrict__ H, int n) {
    int lane = threadIdx.x & 63;
    int row0 = blockIdx.x * 64 + (threadIdx.x >> 6) * 16;
    int m = lane & 15, g = lane >> 4;
    f32x4 acc[NCT];
#pragma unroll
    for (int ct = 0; ct < NCT; ct++) acc[ct] = (f32x4){0.f, 0.f, 0.f, 0.f};

    int ar = row0 + m;
    if (ar >= n) ar = 0;
    const AT* arow = A + (size_t)ar * 128 + g * 8;
    const f16x8* bp = (const f16x8*)wf;
#pragma unroll
    for (int ks = 0; ks < 4; ks++) {
        f16x8 af;
        if constexpr (sizeof(AT) == 4) {
            const float4* p = (const float4*)(arow + ks * 32);
            float4 a = p[0], b = p[1];
            af[0] = (f16)a.x; af[1] = (f16)a.y; af[2] = (f16)a.z; af[3] = (f16)a.w;
            af[4] = (f16)b.x; af[5] = (f16)b.y; af[6] = (f16)b.z; af[7] = (f16)b.w;
        } else {
            af = *(const f16x8*)(arow + ks * 32);
        }
#pragma unroll
        for (int ct = 0; ct < NCT; ct++) {
            f16x8 bf = bp[(ks * NCT + ct) * 64 + lane];
            acc[ct] = __builtin_amdgcn_mfma_f32_16x16x32_f16(af, bf, acc[ct], 0, 0, 0);
        }
    }
#pragma unroll
    for (int ct = 0; ct < NCT; ct++)
#pragma unroll
        for (int r = 0; r < 4; r++) {
            int orow = row0 + g * 4 + r;
            if (orow < n) H[(size_t)orow * (NCT * 16) + ct * 16 + m] = (f16)acc[ct][r];
        }
}

// ---------------------------------------------------------------------------
// Per-node attention half-scores from f16 features
// ---------------------------------------------------------------------------
template <int HEADS, int CH>
__global__ void att_scores(const f16* __restrict__ H, const float* __restrict__ att_s,
                           const float* __restrict__ att_d, float* __restrict__ a_s,
                           float* __restrict__ a_d, int n) {
    int idx = blockIdx.x * blockDim.x + threadIdx.x;
    if (idx >= n * HEADS) return;
    int node = idx / HEADS;
    int h = idx - node * HEADS;
    const f16x8* hp = (const f16x8*)(H + (size_t)node * (HEADS * CH) + h * CH);
    float s = 0.f, d = 0.f;
#pragma unroll
    for (int c8 = 0; c8 < CH / 8; c8++) {
        f16x8 v = hp[c8];
#pragma unroll
        for (int j = 0; j < 8; j++) {
            float x = (float)v[j];
            s = fmaf(x, att_s[h * CH + c8 * 8 + j], s);
            d = fmaf(x, att_d[h * CH + c8 * 8 + j], d);
        }
    }
    a_s[idx] = s;
    a_d[idx] = d;
}

// ---------------------------------------------------------------------------
// Layer 1 fused aggregation (f16 gathers): one wave per dst node.
// lane -> channels [2l, 2l+1]; head = lane>>3. Epilogue: +bias, ReLU, f16 out.
// ---------------------------------------------------------------------------
__global__ __launch_bounds__(256) void aggr1_k(const int* __restrict__ rp,
                                               const int* __restrict__ csrc,
                                               const float* __restrict__ a_s,
                                               const float* __restrict__ a_d,
                                               const f16* __restrict__ h,
                                               const float* __restrict__ bias,
                                               f16* __restrict__ out) {
    int lane = threadIdx.x & 63;
    int d = blockIdx.x * 4 + (threadIdx.x >> 6);
    if (d >= N_NODES) return;
    int head = lane >> 3;
    const f16x2* hh = (const f16x2*)h;

    float ed = a_d[d * 8 + head];
    float e = a_s[d * 8 + head] + ed;
    e = e > 0.f ? e : NEG_SLOPE * e;
    float w = __expf(e);
    f16x2 hv = hh[(size_t)d * 64 + lane];
    float den = w;
    float nx = w * (float)hv[0], ny = w * (float)hv[1];

    int beg = rp[d], end = rp[d + 1];
    int i = beg;
    for (; i + 2 <= end; i += 2) {
        int s0 = csrc[i], s1 = csrc[i + 1];
        float e0 = a_s[s0 * 8 + head] + ed;
        float e1 = a_s[s1 * 8 + head] + ed;
        e0 = e0 > 0.f ? e0 : NEG_SLOPE * e0;
        e1 = e1 > 0.f ? e1 : NEG_SLOPE * e1;
        float w0 = __expf(e0), w1 = __expf(e1);
        f16x2 v0 = hh[(size_t)s0 * 64 + lane];
        f16x2 v1 = hh[(size_t)s1 * 64 + lane];
        den += w0 + w1;
        nx = fmaf(w0, (float)v0[0], nx);
        ny = fmaf(w0, (float)v0[1], ny);
        nx = fmaf(w1, (float)v1[0], nx);
        ny = fmaf(w1, (float)v1[1], ny);
    }
    if (i < end) {
        int s0 = csrc[i];
        float e0 = a_s[s0 * 8 + head] + ed;
        e0 = e0 > 0.f ? e0 : NEG_SLOPE * e0;
        float w0 = __expf(e0);
        f16x2 v0 = hh[(size_t)s0 * 64 + lane];
        den += w0;
        nx = fmaf(w0, (float)v0[0], nx);
        ny = fmaf(w0, (float)v0[1], ny);
    }
    float inv = 1.f / (den + 1e-16f);
    float2 b = ((const float2*)bias)[lane];
    f16x2 r;
    r[0] = (f16)fmaxf(fmaf(nx, inv, b.x), 0.f);
    r[1] = (f16)fmaxf(fmaf(ny, inv, b.y), 0.f);
    ((f16x2*)out)[(size_t)d * 64 + lane] = r;
}

// ---------------------------------------------------------------------------
// Layer 2 fused aggregation + bias + log_softmax: one wave per node, lane=ch.
// ---------------------------------------------------------------------------
__global__ __launch_bounds__(256) void aggr2_k(const int* __restrict__ rp,
                                               const int* __restrict__ csrc,
                                               const float* __restrict__ a_s,
                                               const float* __restrict__ a_d,
                                               const f16* __restrict__ h,
                                               const float* __restrict__ bias,
                                               float* __restrict__ out) {
    int lane = threadIdx.x & 63;
    int d = blockIdx.x * 4 + (threadIdx.x >> 6);
    if (d >= N_NODES) return;

    float ed = a_d[d];
    float e = a_s[d] + ed;
    e = e > 0.f ? e : NEG_SLOPE * e;
    float w = __expf(e);
    float den = w;
    float num = w * (float)h[(size_t)d * 64 + lane];

    int beg = rp[d], end = rp[d + 1];
    int i = beg;
    for (; i + 2 <= end; i += 2) {
        int s0 = csrc[i], s1 = csrc[i + 1];
        float e0 = a_s[s0] + ed, e1 = a_s[s1] + ed;
        e0 = e0 > 0.f ? e0 : NEG_SLOPE * e0;
        e1 = e1 > 0.f ? e1 : NEG_SLOPE * e1;
        float w0 = __expf(e0), w1 = __expf(e1);
        float v0 = (float)h[(size_t)s0 * 64 + lane];
        float v1 = (float)h[(size_t)s1 * 64 + lane];
        den += w0 + w1;
        num = fmaf(w0, v0, num);
        num = fmaf(w1, v1, num);
    }
    if (i < end) {
        int s0 = csrc[i];
        float e0 = a_s[s0] + ed;
        e0 = e0 > 0.f ? e0 : NEG_SLOPE * e0;
        float w0 = __expf(e0);
        den += w0;
        num = fmaf(w0, (float)h[(size_t)s0 * 64 + lane], num);
    }
    float z = num / (den + 1e-16f) + bias[lane];

    float m = z;
#pragma unroll
    for (int o = 32; o > 0; o >>= 1) m = fmaxf(m, __shfl_xor(m, o, 64));
    float p = __expf(z - m);
    float ssum = p;
#pragma unroll
    for (int o = 32; o > 0; o >>= 1) ssum += __shfl_xor(ssum, o, 64);
    out[(size_t)d * 64 + lane] = z - m - logf(ssum);
}

// ---------------------------------------------------------------------------
extern "C" void kernel_launch(void* const* d_in, const int* in_sizes, int n_in,
                              void* d_out, int out_size, void* d_ws, size_t ws_size,
                              hipStream_t stream) {
    const float* x   = (const float*)d_in[0];
    const void*  ei  = d_in[1];
    const float* W1  = (const float*)d_in[2];
    const float* as1 = (const float*)d_in[3];
    const float* ad1 = (const float*)d_in[4];
    const float* b1  = (const float*)d_in[5];
    const float* W2  = (const float*)d_in[6];
    const float* as2 = (const float*)d_in[7];
    const float* ad2 = (const float*)d_in[8];
    const float* b2  = (const float*)d_in[9];
    float* out = (float*)d_out;

    // workspace layout
    f16*   h1   = (f16*)d_ws;                             // N*128 f16 (reused as h2)
    f16*   out1 = h1 + (size_t)N_NODES * 128;             // N*128 f16
    f16*   w1f  = out1 + (size_t)N_NODES * 128;           // 16384 f16
    f16*   w2f  = w1f + 16384;                            // 8192 f16
    float* a_s  = (float*)(w2f + 8192);                   // N*8 f32
    float* a_d  = a_s + (size_t)N_NODES * 8;              // N*8 f32
    int*   rp   = (int*)(a_d + (size_t)N_NODES * 8);      // N+1 (+pad)
    int*   deg  = rp + (N_NODES + 64);                    // N
    int*   bsum = deg + N_NODES;                          // 128
    int*   csrc = bsum + 128;                             // E
    int*   rank = csrc + N_EDGES;                         // E
    f16*   h2   = h1;

    // --- CSR build (by dst): rank -> scan -> place ---
    hipMemsetAsync(deg, 0, (size_t)N_NODES * sizeof(int), stream);
    {
        int threads = (N_EDGES + 3) / 4;
        rank_k<<<(threads + 255) / 256, 256, 0, stream>>>(ei, deg, rank);
    }
    scan1_k<<<SCAN_NBLK, SCAN_BLK, 0, stream>>>(deg, rp, bsum);
    scan2_k<<<1, 128, 0, stream>>>(bsum);
    scan3_k<<<(N_NODES + 255) / 256, 256, 0, stream>>>(rp, bsum);
    {
        int threads = (N_EDGES + 3) / 4;
        scatter2_k<<<(threads + 255) / 256, 256, 0, stream>>>(ei, rp, rank, csrc);
    }

    // --- weight fragment prep ---
    cvt_wfrag_k<8><<<(4 * 8 * 512 + 255) / 256, 256, 0, stream>>>(W1, w1f);
    cvt_wfrag_k<4><<<(4 * 4 * 512 + 255) / 256, 256, 0, stream>>>(W2, w2f);

    // --- layer 1 (gemm reads f32 x, converts in-flight) ---
    gemm_mfma<8, float><<<(N_NODES + 63) / 64, 256, 0, stream>>>(x, w1f, h1, N_NODES);
    att_scores<8, 16><<<(N_NODES * 8 + 255) / 256, 256, 0, stream>>>(h1, as1, ad1, a_s, a_d, N_NODES);
    aggr1_k<<<(N_NODES + 3) / 4, 256, 0, stream>>>(rp, csrc, a_s, a_d, h1, b1, out1);

    // --- layer 2 (fused bias + log_softmax) ---
    gemm_mfma<4, f16><<<(N_NODES + 63) / 64, 256, 0, stream>>>(out1, w2f, h2, N_NODES);
    att_scores<1, 64><<<(N_NODES + 255) / 256, 256, 0, stream>>>(h2, as2, ad2, a_s, a_d, N_NODES);
    aggr2_k<<<(N_NODES + 3) / 4, 256, 0, stream>>>(rp, csrc, a_s, a_d, h2, b2, out);
}

// Round 5
// 288.847 us; speedup vs baseline: 7.0879x; 1.2588x over previous
//
#include <hip/hip_runtime.h>
#include <hip/hip_bf16.h>

#define N_NODES 100000
#define N_EDGES 1600000
#define NEG_SLOPE 0.2f

#define SCAN_ITEMS 4
#define SCAN_BLK 256
#define SCAN_CHUNK (SCAN_BLK * SCAN_ITEMS)                      // 1024
#define SCAN_NBLK ((N_NODES + SCAN_CHUNK - 1) / SCAN_CHUNK)     // 98

typedef _Float16 f16;
typedef _Float16 f16x8 __attribute__((ext_vector_type(8)));
typedef _Float16 f16x2 __attribute__((ext_vector_type(2)));
typedef float f32x4 __attribute__((ext_vector_type(4)));
typedef float f32x2v __attribute__((ext_vector_type(2)));

// ---------------------------------------------------------------------------
// Edge dtype probe (int64 reference vs possible int32 delivery)
// ---------------------------------------------------------------------------
__device__ __forceinline__ bool edges_are_i64(const void* p) {
    const unsigned long long* q = (const unsigned long long*)p;
    bool ok = true;
#pragma unroll
    for (int i = 0; i < 8; i++)
        if (q[i] >= (unsigned long long)N_NODES) ok = false;
    return ok;
}
__device__ __forceinline__ int edge_src(const void* ei, int j, bool i64) {
    return i64 ? (int)((const long long*)ei)[j] : ((const int*)ei)[j];
}
__device__ __forceinline__ int edge_dst(const void* ei, int j, bool i64) {
    return i64 ? (int)((const long long*)ei)[N_EDGES + j] : ((const int*)ei)[N_EDGES + j];
}

// ---------------------------------------------------------------------------
// CSR build pass A: degree histogram + per-edge rank (coalesced write).
// ---------------------------------------------------------------------------
__global__ void rank_k(const void* __restrict__ ei, int* __restrict__ deg,
                       int* __restrict__ rank) {
    bool i64 = edges_are_i64(ei);
    int tid = blockIdx.x * blockDim.x + threadIdx.x;
    int stride = gridDim.x * blockDim.x;
#pragma unroll
    for (int u = 0; u < 4; u++) {
        int j = tid + u * stride;
        if (j < N_EDGES) rank[j] = atomicAdd(&deg[edge_dst(ei, j, i64)], 1);
    }
}

// ---------------------------------------------------------------------------
// CSR build pass B: placement. No atomics, fire-and-forget stores.
// ---------------------------------------------------------------------------
__global__ void scatter2_k(const void* __restrict__ ei, const int* __restrict__ rp,
                           const int* __restrict__ rank, int* __restrict__ csrc) {
    bool i64 = edges_are_i64(ei);
    int tid = blockIdx.x * blockDim.x + threadIdx.x;
    int stride = gridDim.x * blockDim.x;
#pragma unroll
    for (int u = 0; u < 4; u++) {
        int j = tid + u * stride;
        if (j < N_EDGES)
            csrc[rp[edge_dst(ei, j, i64)] + rank[j]] = edge_src(ei, j, i64);
    }
}

// ---------------------------------------------------------------------------
// Block scan over degrees -> row pointers
// ---------------------------------------------------------------------------
__global__ __launch_bounds__(SCAN_BLK) void scan1_k(const int* __restrict__ deg,
                                                    int* __restrict__ rp,
                                                    int* __restrict__ bsum) {
    __shared__ int lds[SCAN_BLK];
    int t = threadIdx.x, b = blockIdx.x;
    int base = b * SCAN_CHUNK + t * SCAN_ITEMS;
    int v[SCAN_ITEMS];
    int s = 0;
#pragma unroll
    for (int i = 0; i < SCAN_ITEMS; i++) {
        v[i] = (base + i < N_NODES) ? deg[base + i] : 0;
        s += v[i];
    }
    lds[t] = s;
    __syncthreads();
    for (int o = 1; o < SCAN_BLK; o <<= 1) {
        int x = (t >= o) ? lds[t - o] : 0;
        __syncthreads();
        lds[t] += x;
        __syncthreads();
    }
    if (t == SCAN_BLK - 1) bsum[b] = lds[t];
    int run = lds[t] - s;
#pragma unroll
    for (int i = 0; i < SCAN_ITEMS; i++) {
        if (base + i < N_NODES) rp[base + i] = run;
        run += v[i];
    }
}

__global__ __launch_bounds__(128) void scan2_k(int* __restrict__ bsum) {
    __shared__ int lds[128];
    int t = threadIdx.x;
    int v = (t < SCAN_NBLK) ? bsum[t] : 0;
    lds[t] = v;
    __syncthreads();
    for (int o = 1; o < 128; o <<= 1) {
        int x = (t >= o) ? lds[t - o] : 0;
        __syncthreads();
        lds[t] += x;
        __syncthreads();
    }
    if (t < SCAN_NBLK) bsum[t] = lds[t] - v;
}

__global__ void scan3_k(int* __restrict__ rp, const int* __restrict__ bsum) {
    int i = blockIdx.x * blockDim.x + threadIdx.x;
    if (i < N_NODES) rp[i] += bsum[i / SCAN_CHUNK];
    if (i == 0) rp[N_NODES] = N_EDGES;
}

// ---------------------------------------------------------------------------
// Pre-shuffle W[K=128 x M=NCT*16] into MFMA B-fragment order
// ---------------------------------------------------------------------------
template <int NCT>
__global__ void cvt_wfrag_k(const float* __restrict__ W, f16* __restrict__ wf) {
    int idx = blockIdx.x * blockDim.x + threadIdx.x;
    if (idx >= 4 * NCT * 512) return;
    int j = idx & 7;
    int lane = (idx >> 3) & 63;
    int ct = (idx >> 9) % NCT;
    int ks = (idx >> 9) / NCT;
    int k = ks * 32 + 8 * (lane >> 4) + j;
    int col = ct * 16 + (lane & 15);
    wf[idx] = (f16)W[k * (NCT * 16) + col];
}

// ---------------------------------------------------------------------------
// MFMA GEMM: H[n x NCT*16] = A[n x 128] @ W. 4 waves x 16 rows per block.
// ---------------------------------------------------------------------------
template <int NCT, typename AT>
__global__ __launch_bounds__(256) void gemm_mfma(const AT* __restrict__ A,
                                                 const f16* __restrict__ wf,
                                                 f16* __restrict__ H, int n) {
    int lane = threadIdx.x & 63;
    int row0 = blockIdx.x * 64 + (threadIdx.x >> 6) * 16;
    int m = lane & 15, g = lane >> 4;
    f32x4 acc[NCT];
#pragma unroll
    for (int ct = 0; ct < NCT; ct++) acc[ct] = (f32x4){0.f, 0.f, 0.f, 0.f};

    int ar = row0 + m;
    if (ar >= n) ar = 0;
    const AT* arow = A + (size_t)ar * 128 + g * 8;
    const f16x8* bp = (const f16x8*)wf;
#pragma unroll
    for (int ks = 0; ks < 4; ks++) {
        f16x8 af;
        if constexpr (sizeof(AT) == 4) {
            const float4* p = (const float4*)(arow + ks * 32);
            float4 a = p[0], b = p[1];
            af[0] = (f16)a.x; af[1] = (f16)a.y; af[2] = (f16)a.z; af[3] = (f16)a.w;
            af[4] = (f16)b.x; af[5] = (f16)b.y; af[6] = (f16)b.z; af[7] = (f16)b.w;
        } else {
            af = *(const f16x8*)(arow + ks * 32);
        }
#pragma unroll
        for (int ct = 0; ct < NCT; ct++) {
            f16x8 bf = bp[(ks * NCT + ct) * 64 + lane];
            acc[ct] = __builtin_amdgcn_mfma_f32_16x16x32_f16(af, bf, acc[ct], 0, 0, 0);
        }
    }
#pragma unroll
    for (int ct = 0; ct < NCT; ct++)
#pragma unroll
        for (int r = 0; r < 4; r++) {
            int orow = row0 + g * 4 + r;
            if (orow < n) H[(size_t)orow * (NCT * 16) + ct * 16 + m] = (f16)acc[ct][r];
        }
}

// ---------------------------------------------------------------------------
// Per-node attention half-scores + fp8(e4m3) encode of the feature rows.
// ---------------------------------------------------------------------------
template <int HEADS, int CH>
__global__ void att_scores(const f16* __restrict__ H, const float* __restrict__ att_s,
                           const float* __restrict__ att_d, float* __restrict__ a_s,
                           float* __restrict__ a_d, unsigned char* __restrict__ h8,
                           int n) {
    int idx = blockIdx.x * blockDim.x + threadIdx.x;
    if (idx >= n * HEADS) return;
    int node = idx / HEADS;
    int h = idx - node * HEADS;
    const f16x8* hp = (const f16x8*)(H + (size_t)node * (HEADS * CH) + h * CH);
    float vals[CH];
    float s = 0.f, d = 0.f;
#pragma unroll
    for (int c8 = 0; c8 < CH / 8; c8++) {
        f16x8 v = hp[c8];
#pragma unroll
        for (int j = 0; j < 8; j++) {
            float x = (float)v[j];
            vals[c8 * 8 + j] = x;
            s = fmaf(x, att_s[h * CH + c8 * 8 + j], s);
            d = fmaf(x, att_d[h * CH + c8 * 8 + j], d);
        }
    }
    a_s[idx] = s;
    a_d[idx] = d;

    // encode CH channels to fp8 (pairs via v_cvt_pk_fp8_f32), 16B stores
    int4* dst = (int4*)(h8 + (size_t)node * (HEADS * CH) + h * CH);
#pragma unroll
    for (int t = 0; t < CH / 16; t++) {
        int w[4];
#pragma unroll
        for (int q = 0; q < 4; q++) {
            int u = __builtin_amdgcn_cvt_pk_fp8_f32(vals[t * 16 + 4 * q],
                                                    vals[t * 16 + 4 * q + 1], 0, false);
            u = __builtin_amdgcn_cvt_pk_fp8_f32(vals[t * 16 + 4 * q + 2],
                                                vals[t * 16 + 4 * q + 3], u, true);
            w[q] = u;
        }
        dst[t] = make_int4(w[0], w[1], w[2], w[3]);
    }
}

// ---------------------------------------------------------------------------
// Layer 1 fused aggregation, fp8 gathers, phase-split scores.
// One wave per dst. Phase 1: 8 edges x 8 heads -> one exp per lane.
// Phase 2: lane handles channels [2l,2l+1] (head=l>>3); weights via shfl.
// ---------------------------------------------------------------------------
__global__ __launch_bounds__(256) void aggr1_k(const int* __restrict__ rp,
                                               const int* __restrict__ csrc,
                                               const float* __restrict__ a_s,
                                               const float* __restrict__ a_d,
                                               const unsigned char* __restrict__ h8,
                                               const float* __restrict__ bias,
                                               f16* __restrict__ out) {
    int lane = threadIdx.x & 63;
    int d = blockIdx.x * 4 + (threadIdx.x >> 6);
    if (d >= N_NODES) return;
    int head = lane >> 3;   // value-phase head (channels 2l,2l+1 -> head l>>3)
    int shead = lane & 7;   // score-phase head

    float ed_v = a_d[d * 8 + head];
    float ed_s = a_d[d * 8 + shead];

    // self loop (per-lane, head-aligned)
    float e0 = a_s[d * 8 + head] + ed_v;
    e0 = e0 > 0.f ? e0 : NEG_SLOPE * e0;
    float w0 = __expf(e0);
    unsigned short u0 = *(const unsigned short*)(h8 + (size_t)d * 128 + 2 * lane);
    f32x2v v0 = __builtin_amdgcn_cvt_pk_f32_fp8((int)u0, false);
    float den = w0, nx = w0 * v0[0], ny = w0 * v0[1];

    int beg = rp[d], end = rp[d + 1];
    for (int cbeg = beg; cbeg < end; cbeg += 8) {
        // phase 1: lane (k=lane>>3, h=lane&7) computes w for edge cbeg+k, head h
        int e = cbeg + (lane >> 3);
        int s = 0;
        float w = 0.f;
        if (e < end) {
            s = csrc[e];
            float es = a_s[s * 8 + shead] + ed_s;
            es = es > 0.f ? es : NEG_SLOPE * es;
            w = __expf(es);
        }
        // phase 2: fully unrolled, padded lanes contribute w=0 on node 0
#pragma unroll
        for (int k = 0; k < 8; k++) {
            float we = __shfl(w, k * 8 + head, 64);
            int se = __shfl(s, k * 8, 64);
            unsigned short uu = *(const unsigned short*)(h8 + (size_t)se * 128 + 2 * lane);
            f32x2v v = __builtin_amdgcn_cvt_pk_f32_fp8((int)uu, false);
            den += we;
            nx = fmaf(we, v[0], nx);
            ny = fmaf(we, v[1], ny);
        }
    }
    float inv = 1.f / (den + 1e-16f);
    float2 b = ((const float2*)bias)[lane];
    f16x2 r;
    r[0] = (f16)fmaxf(fmaf(nx, inv, b.x), 0.f);
    r[1] = (f16)fmaxf(fmaf(ny, inv, b.y), 0.f);
    ((f16x2*)out)[(size_t)d * 64 + lane] = r;
}

// ---------------------------------------------------------------------------
// Layer 2 fused aggregation + bias + log_softmax, fp8 gathers, phase-split.
// One wave per dst, lane = channel. Phase 1: 8 edges' exp (8x redundant, free).
// ---------------------------------------------------------------------------
__global__ __launch_bounds__(256) void aggr2_k(const int* __restrict__ rp,
                                               const int* __restrict__ csrc,
                                               const float* __restrict__ a_s,
                                               const float* __restrict__ a_d,
                                               const unsigned char* __restrict__ h8,
                                               const float* __restrict__ bias,
                                               float* __restrict__ out) {
    int lane = threadIdx.x & 63;
    int d = blockIdx.x * 4 + (threadIdx.x >> 6);
    if (d >= N_NODES) return;

    float ed = a_d[d];
    float e0 = a_s[d] + ed;
    e0 = e0 > 0.f ? e0 : NEG_SLOPE * e0;
    float w0 = __expf(e0);
    float v0 = __builtin_amdgcn_cvt_f32_fp8((int)h8[(size_t)d * 64 + lane], 0);
    float den = w0, num = w0 * v0;

    int beg = rp[d], end = rp[d + 1];
    for (int cbeg = beg; cbeg < end; cbeg += 8) {
        int e = cbeg + (lane & 7);
        int s = 0;
        float w = 0.f;
        if (e < end) {
            s = csrc[e];
            float es = a_s[s] + ed;
            es = es > 0.f ? es : NEG_SLOPE * es;
            w = __expf(es);
        }
#pragma unroll
        for (int k = 0; k < 8; k++) {
            float we = __shfl(w, k, 64);
            int se = __shfl(s, k, 64);
            float v = __builtin_amdgcn_cvt_f32_fp8((int)h8[(size_t)se * 64 + lane], 0);
            den += we;
            num = fmaf(we, v, num);
        }
    }
    float z = num / (den + 1e-16f) + bias[lane];

    float m = z;
#pragma unroll
    for (int o = 32; o > 0; o >>= 1) m = fmaxf(m, __shfl_xor(m, o, 64));
    float p = __expf(z - m);
    float ssum = p;
#pragma unroll
    for (int o = 32; o > 0; o >>= 1) ssum += __shfl_xor(ssum, o, 64);
    out[(size_t)d * 64 + lane] = z - m - logf(ssum);
}

// ---------------------------------------------------------------------------
extern "C" void kernel_launch(void* const* d_in, const int* in_sizes, int n_in,
                              void* d_out, int out_size, void* d_ws, size_t ws_size,
                              hipStream_t stream) {
    const float* x   = (const float*)d_in[0];
    const void*  ei  = d_in[1];
    const float* W1  = (const float*)d_in[2];
    const float* as1 = (const float*)d_in[3];
    const float* ad1 = (const float*)d_in[4];
    const float* b1  = (const float*)d_in[5];
    const float* W2  = (const float*)d_in[6];
    const float* as2 = (const float*)d_in[7];
    const float* ad2 = (const float*)d_in[8];
    const float* b2  = (const float*)d_in[9];
    float* out = (float*)d_out;

    // workspace layout
    f16*   h1   = (f16*)d_ws;                             // N*128 f16 (reused as h2)
    f16*   out1 = h1 + (size_t)N_NODES * 128;             // N*128 f16
    unsigned char* h8 = (unsigned char*)(out1 + (size_t)N_NODES * 128);  // N*128 B (reused N*64 in L2)
    f16*   w1f  = (f16*)(h8 + (size_t)N_NODES * 128);     // 16384 f16
    f16*   w2f  = w1f + 16384;                            // 8192 f16
    float* a_s  = (float*)(w2f + 8192);                   // N*8 f32
    float* a_d  = a_s + (size_t)N_NODES * 8;              // N*8 f32
    int*   rp   = (int*)(a_d + (size_t)N_NODES * 8);      // N+1 (+pad)
    int*   deg  = rp + (N_NODES + 64);                    // N
    int*   bsum = deg + N_NODES;                          // 128
    int*   csrc = bsum + 128;                             // E
    int*   rank = csrc + N_EDGES;                         // E
    f16*   h2   = h1;

    // --- CSR build (by dst): rank -> scan -> place ---
    hipMemsetAsync(deg, 0, (size_t)N_NODES * sizeof(int), stream);
    {
        int threads = (N_EDGES + 3) / 4;
        rank_k<<<(threads + 255) / 256, 256, 0, stream>>>(ei, deg, rank);
    }
    scan1_k<<<SCAN_NBLK, SCAN_BLK, 0, stream>>>(deg, rp, bsum);
    scan2_k<<<1, 128, 0, stream>>>(bsum);
    scan3_k<<<(N_NODES + 255) / 256, 256, 0, stream>>>(rp, bsum);
    {
        int threads = (N_EDGES + 3) / 4;
        scatter2_k<<<(threads + 255) / 256, 256, 0, stream>>>(ei, rp, rank, csrc);
    }

    // --- weight fragment prep ---
    cvt_wfrag_k<8><<<(4 * 8 * 512 + 255) / 256, 256, 0, stream>>>(W1, w1f);
    cvt_wfrag_k<4><<<(4 * 4 * 512 + 255) / 256, 256, 0, stream>>>(W2, w2f);

    // --- layer 1 ---
    gemm_mfma<8, float><<<(N_NODES + 63) / 64, 256, 0, stream>>>(x, w1f, h1, N_NODES);
    att_scores<8, 16><<<(N_NODES * 8 + 255) / 256, 256, 0, stream>>>(h1, as1, ad1, a_s, a_d, h8, N_NODES);
    aggr1_k<<<(N_NODES + 3) / 4, 256, 0, stream>>>(rp, csrc, a_s, a_d, h8, b1, out1);

    // --- layer 2 (fused bias + log_softmax) ---
    gemm_mfma<4, f16><<<(N_NODES + 63) / 64, 256, 0, stream>>>(out1, w2f, h2, N_NODES);
    att_scores<1, 64><<<(N_NODES + 255) / 256, 256, 0, stream>>>(h2, as2, ad2, a_s, a_d, h8, N_NODES);
    aggr2_k<<<(N_NODES + 3) / 4, 256, 0, stream>>>(rp, csrc, a_s, a_d, h8, b2, out);
}

// Round 6
// 286.585 us; speedup vs baseline: 7.1438x; 1.0079x over previous
//
#include <hip/hip_runtime.h>
#include <hip/hip_bf16.h>

#define N_NODES 100000
#define N_EDGES 1600000
#define NEG_SLOPE 0.2f

#define DSTR 16   // deg[] padding: one counter per 64B line (same-line atomic serialization fix)

#define SCAN_ITEMS 4
#define SCAN_BLK 256
#define SCAN_CHUNK (SCAN_BLK * SCAN_ITEMS)                      // 1024
#define SCAN_NBLK ((N_NODES + SCAN_CHUNK - 1) / SCAN_CHUNK)     // 98

typedef _Float16 f16;
typedef _Float16 f16x8 __attribute__((ext_vector_type(8)));
typedef _Float16 f16x2 __attribute__((ext_vector_type(2)));
typedef float f32x4 __attribute__((ext_vector_type(4)));
typedef float f32x2v __attribute__((ext_vector_type(2)));

// ---------------------------------------------------------------------------
// Edge dtype probe (int64 reference vs possible int32 delivery)
// ---------------------------------------------------------------------------
__device__ __forceinline__ bool edges_are_i64(const void* p) {
    const unsigned long long* q = (const unsigned long long*)p;
    bool ok = true;
#pragma unroll
    for (int i = 0; i < 8; i++)
        if (q[i] >= (unsigned long long)N_NODES) ok = false;
    return ok;
}
__device__ __forceinline__ int edge_src(const void* ei, int j, bool i64) {
    return i64 ? (int)((const long long*)ei)[j] : ((const int*)ei)[j];
}
__device__ __forceinline__ int edge_dst(const void* ei, int j, bool i64) {
    return i64 ? (int)((const long long*)ei)[N_EDGES + j] : ((const int*)ei)[N_EDGES + j];
}

// ---------------------------------------------------------------------------
// CSR build pass A: degree histogram (line-padded) + per-edge rank.
// 8 edges/thread grid-stride for atomic-latency ILP.
// ---------------------------------------------------------------------------
__global__ void rank_k(const void* __restrict__ ei, int* __restrict__ deg,
                       int* __restrict__ rank) {
    bool i64 = edges_are_i64(ei);
    int tid = blockIdx.x * blockDim.x + threadIdx.x;
    int stride = gridDim.x * blockDim.x;
#pragma unroll
    for (int u = 0; u < 8; u++) {
        int j = tid + u * stride;
        if (j < N_EDGES)
            rank[j] = atomicAdd(&deg[edge_dst(ei, j, i64) * DSTR], 1);
    }
}

// ---------------------------------------------------------------------------
// CSR build pass B: placement. No atomics, fire-and-forget stores.
// ---------------------------------------------------------------------------
__global__ void scatter2_k(const void* __restrict__ ei, const int* __restrict__ rp,
                           const int* __restrict__ rank, int* __restrict__ csrc) {
    bool i64 = edges_are_i64(ei);
    int tid = blockIdx.x * blockDim.x + threadIdx.x;
    int stride = gridDim.x * blockDim.x;
#pragma unroll
    for (int u = 0; u < 8; u++) {
        int j = tid + u * stride;
        if (j < N_EDGES)
            csrc[rp[edge_dst(ei, j, i64)] + rank[j]] = edge_src(ei, j, i64);
    }
}

// ---------------------------------------------------------------------------
// Block scan over (padded) degrees -> row pointers
// ---------------------------------------------------------------------------
__global__ __launch_bounds__(SCAN_BLK) void scan1_k(const int* __restrict__ deg,
                                                    int* __restrict__ rp,
                                                    int* __restrict__ bsum) {
    __shared__ int lds[SCAN_BLK];
    int t = threadIdx.x, b = blockIdx.x;
    int base = b * SCAN_CHUNK + t * SCAN_ITEMS;
    int v[SCAN_ITEMS];
    int s = 0;
#pragma unroll
    for (int i = 0; i < SCAN_ITEMS; i++) {
        v[i] = (base + i < N_NODES) ? deg[(base + i) * DSTR] : 0;
        s += v[i];
    }
    lds[t] = s;
    __syncthreads();
    for (int o = 1; o < SCAN_BLK; o <<= 1) {
        int x = (t >= o) ? lds[t - o] : 0;
        __syncthreads();
        lds[t] += x;
        __syncthreads();
    }
    if (t == SCAN_BLK - 1) bsum[b] = lds[t];
    int run = lds[t] - s;
#pragma unroll
    for (int i = 0; i < SCAN_ITEMS; i++) {
        if (base + i < N_NODES) rp[base + i] = run;
        run += v[i];
    }
}

__global__ __launch_bounds__(128) void scan2_k(int* __restrict__ bsum) {
    __shared__ int lds[128];
    int t = threadIdx.x;
    int v = (t < SCAN_NBLK) ? bsum[t] : 0;
    lds[t] = v;
    __syncthreads();
    for (int o = 1; o < 128; o <<= 1) {
        int x = (t >= o) ? lds[t - o] : 0;
        __syncthreads();
        lds[t] += x;
        __syncthreads();
    }
    if (t < SCAN_NBLK) bsum[t] = lds[t] - v;
}

__global__ void scan3_k(int* __restrict__ rp, const int* __restrict__ bsum) {
    int i = blockIdx.x * blockDim.x + threadIdx.x;
    if (i < N_NODES) rp[i] += bsum[i / SCAN_CHUNK];
    if (i == 0) rp[N_NODES] = N_EDGES;
}

// ---------------------------------------------------------------------------
// Pre-shuffle W[K=128 x M=NCT*16] into MFMA B-fragment order
// ---------------------------------------------------------------------------
template <int NCT>
__global__ void cvt_wfrag_k(const float* __restrict__ W, f16* __restrict__ wf) {
    int idx = blockIdx.x * blockDim.x + threadIdx.x;
    if (idx >= 4 * NCT * 512) return;
    int j = idx & 7;
    int lane = (idx >> 3) & 63;
    int ct = (idx >> 9) % NCT;
    int ks = (idx >> 9) / NCT;
    int k = ks * 32 + 8 * (lane >> 4) + j;
    int col = ct * 16 + (lane & 15);
    wf[idx] = (f16)W[k * (NCT * 16) + col];
}

// ---------------------------------------------------------------------------
// MFMA GEMM: H[n x NCT*16] = A[n x 128] @ W. 4 waves x 16 rows per block.
// ---------------------------------------------------------------------------
template <int NCT, typename AT>
__global__ __launch_bounds__(256) void gemm_mfma(const AT* __restrict__ A,
                                                 const f16* __restrict__ wf,
                                                 f16* __restrict__ H, int n) {
    int lane = threadIdx.x & 63;
    int row0 = blockIdx.x * 64 + (threadIdx.x >> 6) * 16;
    int m = lane & 15, g = lane >> 4;
    f32x4 acc[NCT];
#pragma unroll
    for (int ct = 0; ct < NCT; ct++) acc[ct] = (f32x4){0.f, 0.f, 0.f, 0.f};

    int ar = row0 + m;
    if (ar >= n) ar = 0;
    const AT* arow = A + (size_t)ar * 128 + g * 8;
    const f16x8* bp = (const f16x8*)wf;
#pragma unroll
    for (int ks = 0; ks < 4; ks++) {
        f16x8 af;
        if constexpr (sizeof(AT) == 4) {
            const float4* p = (const float4*)(arow + ks * 32);
            float4 a = p[0], b = p[1];
            af[0] = (f16)a.x; af[1] = (f16)a.y; af[2] = (f16)a.z; af[3] = (f16)a.w;
            af[4] = (f16)b.x; af[5] = (f16)b.y; af[6] = (f16)b.z; af[7] = (f16)b.w;
        } else {
            af = *(const f16x8*)(arow + ks * 32);
        }
#pragma unroll
        for (int ct = 0; ct < NCT; ct++) {
            f16x8 bf = bp[(ks * NCT + ct) * 64 + lane];
            acc[ct] = __builtin_amdgcn_mfma_f32_16x16x32_f16(af, bf, acc[ct], 0, 0, 0);
        }
    }
#pragma unroll
    for (int ct = 0; ct < NCT; ct++)
#pragma unroll
        for (int r = 0; r < 4; r++) {
            int orow = row0 + g * 4 + r;
            if (orow < n) H[(size_t)orow * (NCT * 16) + ct * 16 + m] = (f16)acc[ct][r];
        }
}

// ---------------------------------------------------------------------------
// Per-node attention half-scores + fp8(e4m3) encode of the feature rows.
// ---------------------------------------------------------------------------
template <int HEADS, int CH>
__global__ void att_scores(const f16* __restrict__ H, const float* __restrict__ att_s,
                           const float* __restrict__ att_d, float* __restrict__ a_s,
                           float* __restrict__ a_d, unsigned char* __restrict__ h8,
                           int n) {
    int idx = blockIdx.x * blockDim.x + threadIdx.x;
    if (idx >= n * HEADS) return;
    int node = idx / HEADS;
    int h = idx - node * HEADS;
    const f16x8* hp = (const f16x8*)(H + (size_t)node * (HEADS * CH) + h * CH);
    float vals[CH];
    float s = 0.f, d = 0.f;
#pragma unroll
    for (int c8 = 0; c8 < CH / 8; c8++) {
        f16x8 v = hp[c8];
#pragma unroll
        for (int j = 0; j < 8; j++) {
            float x = (float)v[j];
            vals[c8 * 8 + j] = x;
            s = fmaf(x, att_s[h * CH + c8 * 8 + j], s);
            d = fmaf(x, att_d[h * CH + c8 * 8 + j], d);
        }
    }
    a_s[idx] = s;
    a_d[idx] = d;

    // encode CH channels to fp8 (pairs via v_cvt_pk_fp8_f32), 16B stores
    int4* dst = (int4*)(h8 + (size_t)node * (HEADS * CH) + h * CH);
#pragma unroll
    for (int t = 0; t < CH / 16; t++) {
        int w[4];
#pragma unroll
        for (int q = 0; q < 4; q++) {
            int u = __builtin_amdgcn_cvt_pk_fp8_f32(vals[t * 16 + 4 * q],
                                                    vals[t * 16 + 4 * q + 1], 0, false);
            u = __builtin_amdgcn_cvt_pk_fp8_f32(vals[t * 16 + 4 * q + 2],
                                                vals[t * 16 + 4 * q + 3], u, true);
            w[q] = u;
        }
        dst[t] = make_int4(w[0], w[1], w[2], w[3]);
    }
}

// ---------------------------------------------------------------------------
// Layer 1 fused aggregation, fp8 gathers, phase-split scores.
// ---------------------------------------------------------------------------
__global__ __launch_bounds__(256) void aggr1_k(const int* __restrict__ rp,
                                               const int* __restrict__ csrc,
                                               const float* __restrict__ a_s,
                                               const float* __restrict__ a_d,
                                               const unsigned char* __restrict__ h8,
                                               const float* __restrict__ bias,
                                               f16* __restrict__ out) {
    int lane = threadIdx.x & 63;
    int d = blockIdx.x * 4 + (threadIdx.x >> 6);
    if (d >= N_NODES) return;
    int head = lane >> 3;   // value-phase head (channels 2l,2l+1 -> head l>>3)
    int shead = lane & 7;   // score-phase head

    float ed_v = a_d[d * 8 + head];
    float ed_s = a_d[d * 8 + shead];

    float e0 = a_s[d * 8 + head] + ed_v;
    e0 = e0 > 0.f ? e0 : NEG_SLOPE * e0;
    float w0 = __expf(e0);
    unsigned short u0 = *(const unsigned short*)(h8 + (size_t)d * 128 + 2 * lane);
    f32x2v v0 = __builtin_amdgcn_cvt_pk_f32_fp8((int)u0, false);
    float den = w0, nx = w0 * v0[0], ny = w0 * v0[1];

    int beg = rp[d], end = rp[d + 1];
    for (int cbeg = beg; cbeg < end; cbeg += 8) {
        int e = cbeg + (lane >> 3);
        int s = 0;
        float w = 0.f;
        if (e < end) {
            s = csrc[e];
            float es = a_s[s * 8 + shead] + ed_s;
            es = es > 0.f ? es : NEG_SLOPE * es;
            w = __expf(es);
        }
#pragma unroll
        for (int k = 0; k < 8; k++) {
            float we = __shfl(w, k * 8 + head, 64);
            int se = __shfl(s, k * 8, 64);
            unsigned short uu = *(const unsigned short*)(h8 + (size_t)se * 128 + 2 * lane);
            f32x2v v = __builtin_amdgcn_cvt_pk_f32_fp8((int)uu, false);
            den += we;
            nx = fmaf(we, v[0], nx);
            ny = fmaf(we, v[1], ny);
        }
    }
    float inv = 1.f / (den + 1e-16f);
    float2 b = ((const float2*)bias)[lane];
    f16x2 r;
    r[0] = (f16)fmaxf(fmaf(nx, inv, b.x), 0.f);
    r[1] = (f16)fmaxf(fmaf(ny, inv, b.y), 0.f);
    ((f16x2*)out)[(size_t)d * 64 + lane] = r;
}

// ---------------------------------------------------------------------------
// Layer 2 fused aggregation + bias + log_softmax, fp8 gathers, phase-split.
// ---------------------------------------------------------------------------
__global__ __launch_bounds__(256) void aggr2_k(const int* __restrict__ rp,
                                               const int* __restrict__ csrc,
                                               const float* __restrict__ a_s,
                                               const float* __restrict__ a_d,
                                               const unsigned char* __restrict__ h8,
                                               const float* __restrict__ bias,
                                               float* __restrict__ out) {
    int lane = threadIdx.x & 63;
    int d = blockIdx.x * 4 + (threadIdx.x >> 6);
    if (d >= N_NODES) return;

    float ed = a_d[d];
    float e0 = a_s[d] + ed;
    e0 = e0 > 0.f ? e0 : NEG_SLOPE * e0;
    float w0 = __expf(e0);
    float v0 = __builtin_amdgcn_cvt_f32_fp8((int)h8[(size_t)d * 64 + lane], 0);
    float den = w0, num = w0 * v0;

    int beg = rp[d], end = rp[d + 1];
    for (int cbeg = beg; cbeg < end; cbeg += 8) {
        int e = cbeg + (lane & 7);
        int s = 0;
        float w = 0.f;
        if (e < end) {
            s = csrc[e];
            float es = a_s[s] + ed;
            es = es > 0.f ? es : NEG_SLOPE * es;
            w = __expf(es);
        }
#pragma unroll
        for (int k = 0; k < 8; k++) {
            float we = __shfl(w, k, 64);
            int se = __shfl(s, k, 64);
            float v = __builtin_amdgcn_cvt_f32_fp8((int)h8[(size_t)se * 64 + lane], 0);
            den += we;
            num = fmaf(we, v, num);
        }
    }
    float z = num / (den + 1e-16f) + bias[lane];

    float m = z;
#pragma unroll
    for (int o = 32; o > 0; o >>= 1) m = fmaxf(m, __shfl_xor(m, o, 64));
    float p = __expf(z - m);
    float ssum = p;
#pragma unroll
    for (int o = 32; o > 0; o >>= 1) ssum += __shfl_xor(ssum, o, 64);
    out[(size_t)d * 64 + lane] = z - m - logf(ssum);
}

// ---------------------------------------------------------------------------
extern "C" void kernel_launch(void* const* d_in, const int* in_sizes, int n_in,
                              void* d_out, int out_size, void* d_ws, size_t ws_size,
                              hipStream_t stream) {
    const float* x   = (const float*)d_in[0];
    const void*  ei  = d_in[1];
    const float* W1  = (const float*)d_in[2];
    const float* as1 = (const float*)d_in[3];
    const float* ad1 = (const float*)d_in[4];
    const float* b1  = (const float*)d_in[5];
    const float* W2  = (const float*)d_in[6];
    const float* as2 = (const float*)d_in[7];
    const float* ad2 = (const float*)d_in[8];
    const float* b2  = (const float*)d_in[9];
    float* out = (float*)d_out;

    // workspace layout
    f16*   h1   = (f16*)d_ws;                             // N*128 f16 (reused as h2)
    f16*   out1 = h1 + (size_t)N_NODES * 128;             // N*128 f16
    unsigned char* h8 = (unsigned char*)(out1 + (size_t)N_NODES * 128);  // N*128 B
    f16*   w1f  = (f16*)(h8 + (size_t)N_NODES * 128);     // 16384 f16
    f16*   w2f  = w1f + 16384;                            // 8192 f16
    float* a_s  = (float*)(w2f + 8192);                   // N*8 f32
    float* a_d  = a_s + (size_t)N_NODES * 8;              // N*8 f32
    int*   rp   = (int*)(a_d + (size_t)N_NODES * 8);      // N+1 (+pad)
    int*   deg  = rp + (N_NODES + 64);                    // N*DSTR (line-padded)
    int*   bsum = deg + (size_t)N_NODES * DSTR;           // 128
    int*   csrc = bsum + 128;                             // E
    int*   rank = csrc + N_EDGES;                         // E
    f16*   h2   = h1;

    // --- CSR build (by dst): rank -> scan -> place ---
    hipMemsetAsync(deg, 0, (size_t)N_NODES * DSTR * sizeof(int), stream);
    {
        int threads = (N_EDGES + 7) / 8;
        rank_k<<<(threads + 255) / 256, 256, 0, stream>>>(ei, deg, rank);
    }
    scan1_k<<<SCAN_NBLK, SCAN_BLK, 0, stream>>>(deg, rp, bsum);
    scan2_k<<<1, 128, 0, stream>>>(bsum);
    scan3_k<<<(N_NODES + 255) / 256, 256, 0, stream>>>(rp, bsum);
    {
        int threads = (N_EDGES + 7) / 8;
        scatter2_k<<<(threads + 255) / 256, 256, 0, stream>>>(ei, rp, rank, csrc);
    }

    // --- weight fragment prep ---
    cvt_wfrag_k<8><<<(4 * 8 * 512 + 255) / 256, 256, 0, stream>>>(W1, w1f);
    cvt_wfrag_k<4><<<(4 * 4 * 512 + 255) / 256, 256, 0, stream>>>(W2, w2f);

    // --- layer 1 ---
    gemm_mfma<8, float><<<(N_NODES + 63) / 64, 256, 0, stream>>>(x, w1f, h1, N_NODES);
    att_scores<8, 16><<<(N_NODES * 8 + 255) / 256, 256, 0, stream>>>(h1, as1, ad1, a_s, a_d, h8, N_NODES);
    aggr1_k<<<(N_NODES + 3) / 4, 256, 0, stream>>>(rp, csrc, a_s, a_d, h8, b1, out1);

    // --- layer 2 (fused bias + log_softmax) ---
    gemm_mfma<4, f16><<<(N_NODES + 63) / 64, 256, 0, stream>>>(out1, w2f, h2, N_NODES);
    att_scores<1, 64><<<(N_NODES + 255) / 256, 256, 0, stream>>>(h2, as2, ad2, a_s, a_d, h8, N_NODES);
    aggr2_k<<<(N_NODES + 3) / 4, 256, 0, stream>>>(rp, csrc, a_s, a_d, h8, b2, out);
}

// Round 7
// 229.370 us; speedup vs baseline: 8.9258x; 1.2494x over previous
//
#include <hip/hip_runtime.h>
#include <hip/hip_bf16.h>

#define N_NODES 100000
#define N_EDGES 1600000
#define NEG_SLOPE 0.2f

// --- bucket sort geometry ---
#define BUCK_SHIFT 7
#define NBUCK ((N_NODES + 127) >> BUCK_SHIFT)     // 782 buckets of 128 nodes
#define B1 256                                    // blocks in hist/scatter stages
#define CHUNK ((N_EDGES + B1 - 1) / B1)           // 6250 edges per block chunk

// --- generic scan geometry (for NBUCK*B1 = 200192 elements) ---
#define SCAN_ITEMS 4
#define SCAN_BLK 256
#define SCAN_CHUNK (SCAN_BLK * SCAN_ITEMS)        // 1024
#define NSCAN (NBUCK * B1)                        // 200192
#define SCAN_NB ((NSCAN + SCAN_CHUNK - 1) / SCAN_CHUNK)  // 196

typedef _Float16 f16;
typedef _Float16 f16x8 __attribute__((ext_vector_type(8)));
typedef _Float16 f16x2 __attribute__((ext_vector_type(2)));
typedef float f32x4 __attribute__((ext_vector_type(4)));
typedef float f32x2v __attribute__((ext_vector_type(2)));

// ---------------------------------------------------------------------------
// Edge dtype probe (int64 reference vs possible int32 delivery)
// ---------------------------------------------------------------------------
__device__ __forceinline__ bool edges_are_i64(const void* p) {
    const unsigned long long* q = (const unsigned long long*)p;
    bool ok = true;
#pragma unroll
    for (int i = 0; i < 8; i++)
        if (q[i] >= (unsigned long long)N_NODES) ok = false;
    return ok;
}
__device__ __forceinline__ int edge_src(const void* ei, int j, bool i64) {
    return i64 ? (int)((const long long*)ei)[j] : ((const int*)ei)[j];
}
__device__ __forceinline__ int edge_dst(const void* ei, int j, bool i64) {
    return i64 ? (int)((const long long*)ei)[N_EDGES + j] : ((const int*)ei)[N_EDGES + j];
}

// ---------------------------------------------------------------------------
// CSR stage 1: per-(bucket, block) histogram via LDS atomics only.
// ---------------------------------------------------------------------------
__global__ __launch_bounds__(256) void bhist_k(const void* __restrict__ ei,
                                               int* __restrict__ bh) {
    __shared__ int hist[NBUCK];
    bool i64 = edges_are_i64(ei);
    int bl = blockIdx.x, t = threadIdx.x;
    for (int i = t; i < NBUCK; i += 256) hist[i] = 0;
    __syncthreads();
    int lo = bl * CHUNK, hi = min(lo + CHUNK, N_EDGES);
    for (int j = lo + t; j < hi; j += 256)
        atomicAdd(&hist[edge_dst(ei, j, i64) >> BUCK_SHIFT], 1);
    __syncthreads();
    for (int i = t; i < NBUCK; i += 256) bh[i * B1 + bl] = hist[i];
}

// ---------------------------------------------------------------------------
// Generic exclusive scan (in-place capable), n elements
// ---------------------------------------------------------------------------
__global__ __launch_bounds__(SCAN_BLK) void scan1_k(const int* __restrict__ in,
                                                    int* __restrict__ outp,
                                                    int* __restrict__ bsum, int n) {
    __shared__ int lds[SCAN_BLK];
    int t = threadIdx.x, b = blockIdx.x;
    int base = b * SCAN_CHUNK + t * SCAN_ITEMS;
    int v[SCAN_ITEMS];
    int s = 0;
#pragma unroll
    for (int i = 0; i < SCAN_ITEMS; i++) {
        v[i] = (base + i < n) ? in[base + i] : 0;
        s += v[i];
    }
    lds[t] = s;
    __syncthreads();
    for (int o = 1; o < SCAN_BLK; o <<= 1) {
        int x = (t >= o) ? lds[t - o] : 0;
        __syncthreads();
        lds[t] += x;
        __syncthreads();
    }
    if (t == SCAN_BLK - 1) bsum[b] = lds[t];
    int run = lds[t] - s;
#pragma unroll
    for (int i = 0; i < SCAN_ITEMS; i++) {
        if (base + i < n) outp[base + i] = run;
        run += v[i];
    }
}

__global__ __launch_bounds__(256) void scan2_k(int* __restrict__ bsum, int nb) {
    __shared__ int lds[256];
    int t = threadIdx.x;
    int v = (t < nb) ? bsum[t] : 0;
    lds[t] = v;
    __syncthreads();
    for (int o = 1; o < 256; o <<= 1) {
        int x = (t >= o) ? lds[t - o] : 0;
        __syncthreads();
        lds[t] += x;
        __syncthreads();
    }
    if (t < nb) bsum[t] = lds[t] - v;
}

__global__ void scan3_k(int* __restrict__ outp, const int* __restrict__ bsum, int n) {
    int i = blockIdx.x * blockDim.x + threadIdx.x;
    if (i < n) outp[i] += bsum[i / SCAN_CHUNK];
}

// ---------------------------------------------------------------------------
// CSR stage 2: scatter edges into bucket-grouped (dst,src) pairs.
// Cursors in LDS (one per bucket), initialized from scanned offsets.
// ---------------------------------------------------------------------------
__global__ __launch_bounds__(256) void bscatter_k(const void* __restrict__ ei,
                                                  const int* __restrict__ s,
                                                  int2* __restrict__ be) {
    __shared__ int cur[NBUCK];
    bool i64 = edges_are_i64(ei);
    int bl = blockIdx.x, t = threadIdx.x;
    for (int i = t; i < NBUCK; i += 256) cur[i] = s[i * B1 + bl];
    __syncthreads();
    int lo = bl * CHUNK, hi = min(lo + CHUNK, N_EDGES);
    for (int j = lo + t; j < hi; j += 256) {
        int d = edge_dst(ei, j, i64);
        int sr = edge_src(ei, j, i64);
        int pos = atomicAdd(&cur[d >> BUCK_SHIFT], 1);
        be[pos] = make_int2(d, sr);
    }
}

// ---------------------------------------------------------------------------
// CSR stage 3: one block per bucket. LDS count over 128 local nodes,
// LDS scan -> rp, then place csrc within the bucket. No global atomics.
// ---------------------------------------------------------------------------
__global__ __launch_bounds__(256) void bcsr_k(const int* __restrict__ s,
                                              const int2* __restrict__ be,
                                              int* __restrict__ rp,
                                              int* __restrict__ csrc) {
    __shared__ int cnt[128];
    __shared__ int pre[128];
    int b = blockIdx.x, t = threadIdx.x;
    int beg = s[b * B1];
    int end = (b == NBUCK - 1) ? N_EDGES : s[(b + 1) * B1];
    if (t < 128) cnt[t] = 0;
    __syncthreads();
    for (int j = beg + t; j < end; j += 256)
        atomicAdd(&cnt[be[j].x & 127], 1);
    __syncthreads();
    if (t < 128) pre[t] = cnt[t];
    __syncthreads();
    for (int o = 1; o < 128; o <<= 1) {
        int x = 0;
        if (t < 128 && t >= o) x = pre[t - o];
        __syncthreads();
        if (t < 128) pre[t] += x;
        __syncthreads();
    }
    if (t < 128) {
        int node = (b << BUCK_SHIFT) + t;
        int excl = pre[t] - cnt[t];
        if (node < N_NODES) rp[node] = beg + excl;
        cnt[t] = excl;  // becomes the placement cursor (bucket-relative)
    }
    if (b == 0 && t == 0) rp[N_NODES] = N_EDGES;
    __syncthreads();
    for (int j = beg + t; j < end; j += 256) {
        int2 e = be[j];
        int pos = beg + atomicAdd(&cnt[e.x & 127], 1);
        csrc[pos] = e.y;
    }
}

// ---------------------------------------------------------------------------
// Pre-shuffle W[K=128 x M=NCT*16] into MFMA B-fragment order
// ---------------------------------------------------------------------------
template <int NCT>
__global__ void cvt_wfrag_k(const float* __restrict__ W, f16* __restrict__ wf) {
    int idx = blockIdx.x * blockDim.x + threadIdx.x;
    if (idx >= 4 * NCT * 512) return;
    int j = idx & 7;
    int lane = (idx >> 3) & 63;
    int ct = (idx >> 9) % NCT;
    int ks = (idx >> 9) / NCT;
    int k = ks * 32 + 8 * (lane >> 4) + j;
    int col = ct * 16 + (lane & 15);
    wf[idx] = (f16)W[k * (NCT * 16) + col];
}

// ---------------------------------------------------------------------------
// MFMA GEMM: H[n x NCT*16] = A[n x 128] @ W. 4 waves x 16 rows per block.
// ---------------------------------------------------------------------------
template <int NCT, typename AT>
__global__ __launch_bounds__(256) void gemm_mfma(const AT* __restrict__ A,
                                                 const f16* __restrict__ wf,
                                                 f16* __restrict__ H, int n) {
    int lane = threadIdx.x & 63;
    int row0 = blockIdx.x * 64 + (threadIdx.x >> 6) * 16;
    int m = lane & 15, g = lane >> 4;
    f32x4 acc[NCT];
#pragma unroll
    for (int ct = 0; ct < NCT; ct++) acc[ct] = (f32x4){0.f, 0.f, 0.f, 0.f};

    int ar = row0 + m;
    if (ar >= n) ar = 0;
    const AT* arow = A + (size_t)ar * 128 + g * 8;
    const f16x8* bp = (const f16x8*)wf;
#pragma unroll
    for (int ks = 0; ks < 4; ks++) {
        f16x8 af;
        if constexpr (sizeof(AT) == 4) {
            const float4* p = (const float4*)(arow + ks * 32);
            float4 a = p[0], b = p[1];
            af[0] = (f16)a.x; af[1] = (f16)a.y; af[2] = (f16)a.z; af[3] = (f16)a.w;
            af[4] = (f16)b.x; af[5] = (f16)b.y; af[6] = (f16)b.z; af[7] = (f16)b.w;
        } else {
            af = *(const f16x8*)(arow + ks * 32);
        }
#pragma unroll
        for (int ct = 0; ct < NCT; ct++) {
            f16x8 bf = bp[(ks * NCT + ct) * 64 + lane];
            acc[ct] = __builtin_amdgcn_mfma_f32_16x16x32_f16(af, bf, acc[ct], 0, 0, 0);
        }
    }
#pragma unroll
    for (int ct = 0; ct < NCT; ct++)
#pragma unroll
        for (int r = 0; r < 4; r++) {
            int orow = row0 + g * 4 + r;
            if (orow < n) H[(size_t)orow * (NCT * 16) + ct * 16 + m] = (f16)acc[ct][r];
        }
}

// ---------------------------------------------------------------------------
// Per-node attention half-scores + fp8(e4m3) encode of the feature rows.
// ---------------------------------------------------------------------------
template <int HEADS, int CH>
__global__ void att_scores(const f16* __restrict__ H, const float* __restrict__ att_s,
                           const float* __restrict__ att_d, float* __restrict__ a_s,
                           float* __restrict__ a_d, unsigned char* __restrict__ h8,
                           int n) {
    int idx = blockIdx.x * blockDim.x + threadIdx.x;
    if (idx >= n * HEADS) return;
    int node = idx / HEADS;
    int h = idx - node * HEADS;
    const f16x8* hp = (const f16x8*)(H + (size_t)node * (HEADS * CH) + h * CH);
    float vals[CH];
    float s = 0.f, d = 0.f;
#pragma unroll
    for (int c8 = 0; c8 < CH / 8; c8++) {
        f16x8 v = hp[c8];
#pragma unroll
        for (int j = 0; j < 8; j++) {
            float x = (float)v[j];
            vals[c8 * 8 + j] = x;
            s = fmaf(x, att_s[h * CH + c8 * 8 + j], s);
            d = fmaf(x, att_d[h * CH + c8 * 8 + j], d);
        }
    }
    a_s[idx] = s;
    a_d[idx] = d;

    int4* dst = (int4*)(h8 + (size_t)node * (HEADS * CH) + h * CH);
#pragma unroll
    for (int t = 0; t < CH / 16; t++) {
        int w[4];
#pragma unroll
        for (int q = 0; q < 4; q++) {
            int u = __builtin_amdgcn_cvt_pk_fp8_f32(vals[t * 16 + 4 * q],
                                                    vals[t * 16 + 4 * q + 1], 0, false);
            u = __builtin_amdgcn_cvt_pk_fp8_f32(vals[t * 16 + 4 * q + 2],
                                                vals[t * 16 + 4 * q + 3], u, true);
            w[q] = u;
        }
        dst[t] = make_int4(w[0], w[1], w[2], w[3]);
    }
}

// ---------------------------------------------------------------------------
// Layer 1 fused aggregation, fp8 gathers, phase-split scores.
// ---------------------------------------------------------------------------
__global__ __launch_bounds__(256) void aggr1_k(const int* __restrict__ rp,
                                               const int* __restrict__ csrc,
                                               const float* __restrict__ a_s,
                                               const float* __restrict__ a_d,
                                               const unsigned char* __restrict__ h8,
                                               const float* __restrict__ bias,
                                               f16* __restrict__ out) {
    int lane = threadIdx.x & 63;
    int d = blockIdx.x * 4 + (threadIdx.x >> 6);
    if (d >= N_NODES) return;
    int head = lane >> 3;
    int shead = lane & 7;

    float ed_v = a_d[d * 8 + head];
    float ed_s = a_d[d * 8 + shead];

    float e0 = a_s[d * 8 + head] + ed_v;
    e0 = e0 > 0.f ? e0 : NEG_SLOPE * e0;
    float w0 = __expf(e0);
    unsigned short u0 = *(const unsigned short*)(h8 + (size_t)d * 128 + 2 * lane);
    f32x2v v0 = __builtin_amdgcn_cvt_pk_f32_fp8((int)u0, false);
    float den = w0, nx = w0 * v0[0], ny = w0 * v0[1];

    int beg = rp[d], end = rp[d + 1];
    for (int cbeg = beg; cbeg < end; cbeg += 8) {
        int e = cbeg + (lane >> 3);
        int s = 0;
        float w = 0.f;
        if (e < end) {
            s = csrc[e];
            float es = a_s[s * 8 + shead] + ed_s;
            es = es > 0.f ? es : NEG_SLOPE * es;
            w = __expf(es);
        }
#pragma unroll
        for (int k = 0; k < 8; k++) {
            float we = __shfl(w, k * 8 + head, 64);
            int se = __shfl(s, k * 8, 64);
            unsigned short uu = *(const unsigned short*)(h8 + (size_t)se * 128 + 2 * lane);
            f32x2v v = __builtin_amdgcn_cvt_pk_f32_fp8((int)uu, false);
            den += we;
            nx = fmaf(we, v[0], nx);
            ny = fmaf(we, v[1], ny);
        }
    }
    float inv = 1.f / (den + 1e-16f);
    float2 b = ((const float2*)bias)[lane];
    f16x2 r;
    r[0] = (f16)fmaxf(fmaf(nx, inv, b.x), 0.f);
    r[1] = (f16)fmaxf(fmaf(ny, inv, b.y), 0.f);
    ((f16x2*)out)[(size_t)d * 64 + lane] = r;
}

// ---------------------------------------------------------------------------
// Layer 2 fused aggregation + bias + log_softmax, fp8 gathers, phase-split.
// ---------------------------------------------------------------------------
__global__ __launch_bounds__(256) void aggr2_k(const int* __restrict__ rp,
                                               const int* __restrict__ csrc,
                                               const float* __restrict__ a_s,
                                               const float* __restrict__ a_d,
                                               const unsigned char* __restrict__ h8,
                                               const float* __restrict__ bias,
                                               float* __restrict__ out) {
    int lane = threadIdx.x & 63;
    int d = blockIdx.x * 4 + (threadIdx.x >> 6);
    if (d >= N_NODES) return;

    float ed = a_d[d];
    float e0 = a_s[d] + ed;
    e0 = e0 > 0.f ? e0 : NEG_SLOPE * e0;
    float w0 = __expf(e0);
    float v0 = __builtin_amdgcn_cvt_f32_fp8((int)h8[(size_t)d * 64 + lane], 0);
    float den = w0, num = w0 * v0;

    int beg = rp[d], end = rp[d + 1];
    for (int cbeg = beg; cbeg < end; cbeg += 8) {
        int e = cbeg + (lane & 7);
        int s = 0;
        float w = 0.f;
        if (e < end) {
            s = csrc[e];
            float es = a_s[s] + ed;
            es = es > 0.f ? es : NEG_SLOPE * es;
            w = __expf(es);
        }
#pragma unroll
        for (int k = 0; k < 8; k++) {
            float we = __shfl(w, k, 64);
            int se = __shfl(s, k, 64);
            float v = __builtin_amdgcn_cvt_f32_fp8((int)h8[(size_t)se * 64 + lane], 0);
            den += we;
            num = fmaf(we, v, num);
        }
    }
    float z = num / (den + 1e-16f) + bias[lane];

    float m = z;
#pragma unroll
    for (int o = 32; o > 0; o >>= 1) m = fmaxf(m, __shfl_xor(m, o, 64));
    float p = __expf(z - m);
    float ssum = p;
#pragma unroll
    for (int o = 32; o > 0; o >>= 1) ssum += __shfl_xor(ssum, o, 64);
    out[(size_t)d * 64 + lane] = z - m - logf(ssum);
}

// ---------------------------------------------------------------------------
extern "C" void kernel_launch(void* const* d_in, const int* in_sizes, int n_in,
                              void* d_out, int out_size, void* d_ws, size_t ws_size,
                              hipStream_t stream) {
    const float* x   = (const float*)d_in[0];
    const void*  ei  = d_in[1];
    const float* W1  = (const float*)d_in[2];
    const float* as1 = (const float*)d_in[3];
    const float* ad1 = (const float*)d_in[4];
    const float* b1  = (const float*)d_in[5];
    const float* W2  = (const float*)d_in[6];
    const float* as2 = (const float*)d_in[7];
    const float* ad2 = (const float*)d_in[8];
    const float* b2  = (const float*)d_in[9];
    float* out = (float*)d_out;

    // workspace layout
    f16*   h1   = (f16*)d_ws;                             // N*128 f16 (reused as h2)
    f16*   out1 = h1 + (size_t)N_NODES * 128;             // N*128 f16
    unsigned char* h8 = (unsigned char*)(out1 + (size_t)N_NODES * 128);  // N*128 B
    f16*   w1f  = (f16*)(h8 + (size_t)N_NODES * 128);     // 16384 f16
    f16*   w2f  = w1f + 16384;                            // 8192 f16
    float* a_s  = (float*)(w2f + 8192);                   // N*8 f32
    float* a_d  = a_s + (size_t)N_NODES * 8;              // N*8 f32
    int*   rp   = (int*)(a_d + (size_t)N_NODES * 8);      // N+1 (+pad to 64)
    int*   bh   = rp + (N_NODES + 64);                    // NBUCK*B1 = 200192
    int*   bsum = bh + NSCAN;                             // 256
    int*   csrc = bsum + 256;                             // E
    int2*  be   = (int2*)(csrc + N_EDGES);                // E int2 (8B aligned)
    f16*   h2   = h1;

    // --- CSR build: LDS-atomic bucket counting sort (no global atomics) ---
    bhist_k<<<B1, 256, 0, stream>>>(ei, bh);
    scan1_k<<<SCAN_NB, SCAN_BLK, 0, stream>>>(bh, bh, bsum, NSCAN);
    scan2_k<<<1, 256, 0, stream>>>(bsum, SCAN_NB);
    scan3_k<<<(NSCAN + 255) / 256, 256, 0, stream>>>(bh, bsum, NSCAN);
    bscatter_k<<<B1, 256, 0, stream>>>(ei, bh, be);
    bcsr_k<<<NBUCK, 256, 0, stream>>>(bh, be, rp, csrc);

    // --- weight fragment prep ---
    cvt_wfrag_k<8><<<(4 * 8 * 512 + 255) / 256, 256, 0, stream>>>(W1, w1f);
    cvt_wfrag_k<4><<<(4 * 4 * 512 + 255) / 256, 256, 0, stream>>>(W2, w2f);

    // --- layer 1 ---
    gemm_mfma<8, float><<<(N_NODES + 63) / 64, 256, 0, stream>>>(x, w1f, h1, N_NODES);
    att_scores<8, 16><<<(N_NODES * 8 + 255) / 256, 256, 0, stream>>>(h1, as1, ad1, a_s, a_d, h8, N_NODES);
    aggr1_k<<<(N_NODES + 3) / 4, 256, 0, stream>>>(rp, csrc, a_s, a_d, h8, b1, out1);

    // --- layer 2 (fused bias + log_softmax) ---
    gemm_mfma<4, f16><<<(N_NODES + 63) / 64, 256, 0, stream>>>(out1, w2f, h2, N_NODES);
    att_scores<1, 64><<<(N_NODES + 255) / 256, 256, 0, stream>>>(h2, as2, ad2, a_s, a_d, h8, N_NODES);
    aggr2_k<<<(N_NODES + 3) / 4, 256, 0, stream>>>(rp, csrc, a_s, a_d, h8, b2, out);
}

// Round 8
// 225.396 us; speedup vs baseline: 9.0832x; 1.0176x over previous
//
#include <hip/hip_runtime.h>
#include <hip/hip_bf16.h>

#define N_NODES 100000
#define N_EDGES 1600000
#define NEG_SLOPE 0.2f

// --- bucket sort geometry ---
#define BUCK_SHIFT 7
#define NBUCK ((N_NODES + 127) >> BUCK_SHIFT)     // 782 buckets of 128 nodes
#define B1 256                                    // blocks in hist/scatter stages
#define CHUNK ((N_EDGES + B1 - 1) / B1)           // 6250 edges per block chunk

// --- generic scan geometry (for NBUCK*B1 = 200192 elements) ---
#define SCAN_ITEMS 4
#define SCAN_BLK 256
#define SCAN_CHUNK (SCAN_BLK * SCAN_ITEMS)        // 1024
#define NSCAN (NBUCK * B1)                        // 200192
#define SCAN_NB ((NSCAN + SCAN_CHUNK - 1) / SCAN_CHUNK)  // 196

typedef _Float16 f16;
typedef _Float16 f16x8 __attribute__((ext_vector_type(8)));
typedef _Float16 f16x2 __attribute__((ext_vector_type(2)));
typedef float f32x4 __attribute__((ext_vector_type(4)));
typedef float f32x2v __attribute__((ext_vector_type(2)));

// ---------------------------------------------------------------------------
// Edge dtype probe (int64 reference vs possible int32 delivery)
// ---------------------------------------------------------------------------
__device__ __forceinline__ bool edges_are_i64(const void* p) {
    const unsigned long long* q = (const unsigned long long*)p;
    bool ok = true;
#pragma unroll
    for (int i = 0; i < 8; i++)
        if (q[i] >= (unsigned long long)N_NODES) ok = false;
    return ok;
}
__device__ __forceinline__ int edge_src(const void* ei, int j, bool i64) {
    return i64 ? (int)((const long long*)ei)[j] : ((const int*)ei)[j];
}
__device__ __forceinline__ int edge_dst(const void* ei, int j, bool i64) {
    return i64 ? (int)((const long long*)ei)[N_EDGES + j] : ((const int*)ei)[N_EDGES + j];
}

// ---------------------------------------------------------------------------
// CSR stage 1: per-(bucket, block) histogram via LDS atomics only.
// ---------------------------------------------------------------------------
__global__ __launch_bounds__(256) void bhist_k(const void* __restrict__ ei,
                                               int* __restrict__ bh) {
    __shared__ int hist[NBUCK];
    bool i64 = edges_are_i64(ei);
    int bl = blockIdx.x, t = threadIdx.x;
    for (int i = t; i < NBUCK; i += 256) hist[i] = 0;
    __syncthreads();
    int lo = bl * CHUNK, hi = min(lo + CHUNK, N_EDGES);
    for (int j = lo + t; j < hi; j += 256)
        atomicAdd(&hist[edge_dst(ei, j, i64) >> BUCK_SHIFT], 1);
    __syncthreads();
    for (int i = t; i < NBUCK; i += 256) bh[i * B1 + bl] = hist[i];
}

// ---------------------------------------------------------------------------
// Generic exclusive scan (in-place capable), n elements
// ---------------------------------------------------------------------------
__global__ __launch_bounds__(SCAN_BLK) void scan1_k(const int* __restrict__ in,
                                                    int* __restrict__ outp,
                                                    int* __restrict__ bsum, int n) {
    __shared__ int lds[SCAN_BLK];
    int t = threadIdx.x, b = blockIdx.x;
    int base = b * SCAN_CHUNK + t * SCAN_ITEMS;
    int v[SCAN_ITEMS];
    int s = 0;
#pragma unroll
    for (int i = 0; i < SCAN_ITEMS; i++) {
        v[i] = (base + i < n) ? in[base + i] : 0;
        s += v[i];
    }
    lds[t] = s;
    __syncthreads();
    for (int o = 1; o < SCAN_BLK; o <<= 1) {
        int x = (t >= o) ? lds[t - o] : 0;
        __syncthreads();
        lds[t] += x;
        __syncthreads();
    }
    if (t == SCAN_BLK - 1) bsum[b] = lds[t];
    int run = lds[t] - s;
#pragma unroll
    for (int i = 0; i < SCAN_ITEMS; i++) {
        if (base + i < n) outp[base + i] = run;
        run += v[i];
    }
}

__global__ __launch_bounds__(256) void scan2_k(int* __restrict__ bsum, int nb) {
    __shared__ int lds[256];
    int t = threadIdx.x;
    int v = (t < nb) ? bsum[t] : 0;
    lds[t] = v;
    __syncthreads();
    for (int o = 1; o < 256; o <<= 1) {
        int x = (t >= o) ? lds[t - o] : 0;
        __syncthreads();
        lds[t] += x;
        __syncthreads();
    }
    if (t < nb) bsum[t] = lds[t] - v;
}

__global__ void scan3_k(int* __restrict__ outp, const int* __restrict__ bsum, int n) {
    int i = blockIdx.x * blockDim.x + threadIdx.x;
    if (i < n) outp[i] += bsum[i / SCAN_CHUNK];
}

// ---------------------------------------------------------------------------
// CSR stage 2: scatter edges into bucket-grouped (dst,src) pairs.
// ---------------------------------------------------------------------------
__global__ __launch_bounds__(256) void bscatter_k(const void* __restrict__ ei,
                                                  const int* __restrict__ s,
                                                  int2* __restrict__ be) {
    __shared__ int cur[NBUCK];
    bool i64 = edges_are_i64(ei);
    int bl = blockIdx.x, t = threadIdx.x;
    for (int i = t; i < NBUCK; i += 256) cur[i] = s[i * B1 + bl];
    __syncthreads();
    int lo = bl * CHUNK, hi = min(lo + CHUNK, N_EDGES);
    for (int j = lo + t; j < hi; j += 256) {
        int d = edge_dst(ei, j, i64);
        int sr = edge_src(ei, j, i64);
        int pos = atomicAdd(&cur[d >> BUCK_SHIFT], 1);
        be[pos] = make_int2(d, sr);
    }
}

// ---------------------------------------------------------------------------
// CSR stage 3: one block per bucket -> rp + csrc. No global atomics.
// ---------------------------------------------------------------------------
__global__ __launch_bounds__(256) void bcsr_k(const int* __restrict__ s,
                                              const int2* __restrict__ be,
                                              int* __restrict__ rp,
                                              int* __restrict__ csrc) {
    __shared__ int cnt[128];
    __shared__ int pre[128];
    int b = blockIdx.x, t = threadIdx.x;
    int beg = s[b * B1];
    int end = (b == NBUCK - 1) ? N_EDGES : s[(b + 1) * B1];
    if (t < 128) cnt[t] = 0;
    __syncthreads();
    for (int j = beg + t; j < end; j += 256)
        atomicAdd(&cnt[be[j].x & 127], 1);
    __syncthreads();
    if (t < 128) pre[t] = cnt[t];
    __syncthreads();
    for (int o = 1; o < 128; o <<= 1) {
        int x = 0;
        if (t < 128 && t >= o) x = pre[t - o];
        __syncthreads();
        if (t < 128) pre[t] += x;
        __syncthreads();
    }
    if (t < 128) {
        int node = (b << BUCK_SHIFT) + t;
        int excl = pre[t] - cnt[t];
        if (node < N_NODES) rp[node] = beg + excl;
        cnt[t] = excl;
    }
    if (b == 0 && t == 0) rp[N_NODES] = N_EDGES;
    __syncthreads();
    for (int j = beg + t; j < end; j += 256) {
        int2 e = be[j];
        int pos = beg + atomicAdd(&cnt[e.x & 127], 1);
        csrc[pos] = e.y;
    }
}

// ---------------------------------------------------------------------------
// Pre-shuffle W[K=128 x M=NCT*16] into MFMA B-fragment order
// ---------------------------------------------------------------------------
template <int NCT>
__global__ void cvt_wfrag_k(const float* __restrict__ W, f16* __restrict__ wf) {
    int idx = blockIdx.x * blockDim.x + threadIdx.x;
    if (idx >= 4 * NCT * 512) return;
    int j = idx & 7;
    int lane = (idx >> 3) & 63;
    int ct = (idx >> 9) % NCT;
    int ks = (idx >> 9) / NCT;
    int k = ks * 32 + 8 * (lane >> 4) + j;
    int col = ct * 16 + (lane & 15);
    wf[idx] = (f16)W[k * (NCT * 16) + col];
}

// ---------------------------------------------------------------------------
// MFMA GEMM: H[n x NCT*16] = A[n x 128] @ W. 4 waves x 16 rows per block.
// ---------------------------------------------------------------------------
template <int NCT, typename AT>
__global__ __launch_bounds__(256) void gemm_mfma(const AT* __restrict__ A,
                                                 const f16* __restrict__ wf,
                                                 f16* __restrict__ H, int n) {
    int lane = threadIdx.x & 63;
    int row0 = blockIdx.x * 64 + (threadIdx.x >> 6) * 16;
    int m = lane & 15, g = lane >> 4;
    f32x4 acc[NCT];
#pragma unroll
    for (int ct = 0; ct < NCT; ct++) acc[ct] = (f32x4){0.f, 0.f, 0.f, 0.f};

    int ar = row0 + m;
    if (ar >= n) ar = 0;
    const AT* arow = A + (size_t)ar * 128 + g * 8;
    const f16x8* bp = (const f16x8*)wf;
#pragma unroll
    for (int ks = 0; ks < 4; ks++) {
        f16x8 af;
        if constexpr (sizeof(AT) == 4) {
            const float4* p = (const float4*)(arow + ks * 32);
            float4 a = p[0], b = p[1];
            af[0] = (f16)a.x; af[1] = (f16)a.y; af[2] = (f16)a.z; af[3] = (f16)a.w;
            af[4] = (f16)b.x; af[5] = (f16)b.y; af[6] = (f16)b.z; af[7] = (f16)b.w;
        } else {
            af = *(const f16x8*)(arow + ks * 32);
        }
#pragma unroll
        for (int ct = 0; ct < NCT; ct++) {
            f16x8 bf = bp[(ks * NCT + ct) * 64 + lane];
            acc[ct] = __builtin_amdgcn_mfma_f32_16x16x32_f16(af, bf, acc[ct], 0, 0, 0);
        }
    }
#pragma unroll
    for (int ct = 0; ct < NCT; ct++)
#pragma unroll
        for (int r = 0; r < 4; r++) {
            int orow = row0 + g * 4 + r;
            if (orow < n) H[(size_t)orow * (NCT * 16) + ct * 16 + m] = (f16)acc[ct][r];
        }
}

// ---------------------------------------------------------------------------
// Per-node attention half-scores + fp8(e4m3) encode of the feature rows.
// ---------------------------------------------------------------------------
template <int HEADS, int CH>
__global__ void att_scores(const f16* __restrict__ H, const float* __restrict__ att_s,
                           const float* __restrict__ att_d, float* __restrict__ a_s,
                           float* __restrict__ a_d, unsigned char* __restrict__ h8,
                           int n) {
    int idx = blockIdx.x * blockDim.x + threadIdx.x;
    if (idx >= n * HEADS) return;
    int node = idx / HEADS;
    int h = idx - node * HEADS;
    const f16x8* hp = (const f16x8*)(H + (size_t)node * (HEADS * CH) + h * CH);
    float vals[CH];
    float s = 0.f, d = 0.f;
#pragma unroll
    for (int c8 = 0; c8 < CH / 8; c8++) {
        f16x8 v = hp[c8];
#pragma unroll
        for (int j = 0; j < 8; j++) {
            float x = (float)v[j];
            vals[c8 * 8 + j] = x;
            s = fmaf(x, att_s[h * CH + c8 * 8 + j], s);
            d = fmaf(x, att_d[h * CH + c8 * 8 + j], d);
        }
    }
    a_s[idx] = s;
    a_d[idx] = d;

    int4* dst = (int4*)(h8 + (size_t)node * (HEADS * CH) + h * CH);
#pragma unroll
    for (int t = 0; t < CH / 16; t++) {
        int w[4];
#pragma unroll
        for (int q = 0; q < 4; q++) {
            int u = __builtin_amdgcn_cvt_pk_fp8_f32(vals[t * 16 + 4 * q],
                                                    vals[t * 16 + 4 * q + 1], 0, false);
            u = __builtin_amdgcn_cvt_pk_fp8_f32(vals[t * 16 + 4 * q + 2],
                                                vals[t * 16 + 4 * q + 3], u, true);
            w[q] = u;
        }
        dst[t] = make_int4(w[0], w[1], w[2], w[3]);
    }
}

// ---------------------------------------------------------------------------
// Layer 1 fused aggregation, fp8 gathers, scalar-broadcast phase split.
// Phase 1: lane = (edge lane&7, head lane>>3) computes one exp.
// Phase 2: weight via static ds_swizzle (src=(l&0x38)|k); row idx via
// readlane -> SGPR -> saddr gather. Lane owns channels [2l,2l+1].
// ---------------------------------------------------------------------------
__global__ __launch_bounds__(256) void aggr1_k(const int* __restrict__ rp,
                                               const int* __restrict__ csrc,
                                               const float* __restrict__ a_s,
                                               const float* __restrict__ a_d,
                                               const unsigned char* __restrict__ h8,
                                               const float* __restrict__ bias,
                                               f16* __restrict__ out) {
    int lane = threadIdx.x & 63;
    int d = blockIdx.x * 4 + (threadIdx.x >> 6);
    if (d >= N_NODES) return;
    int head = lane >> 3;   // head for BOTH phases (value channels 2l,2l+1 -> head l>>3)
    int eidx = lane & 7;    // phase-1 edge slot

    float ed = a_d[d * 8 + head];

    // self loop
    float e0 = a_s[d * 8 + head] + ed;
    e0 = e0 > 0.f ? e0 : NEG_SLOPE * e0;
    float w0 = __expf(e0);
    unsigned short u0 = *(const unsigned short*)(h8 + (size_t)d * 128 + 2 * lane);
    f32x2v v0 = __builtin_amdgcn_cvt_pk_f32_fp8((int)u0, false);
    float den = w0, nx = w0 * v0[0], ny = w0 * v0[1];

    int beg = rp[d], end = rp[d + 1];
    for (int cbeg = beg; cbeg < end; cbeg += 8) {
        int e = cbeg + eidx;
        int s = 0;
        float w = 0.f;
        if (e < end) {
            s = csrc[e];
            float es = a_s[s * 8 + head] + ed;
            es = es > 0.f ? es : NEG_SLOPE * es;
            w = __expf(es);
        }
#define A1_STEP(K)                                                                       \
        {                                                                                \
            float we = __int_as_float(__builtin_amdgcn_ds_swizzle(                        \
                __float_as_int(w), ((K) << 5) | 0x18));                                  \
            int se = __builtin_amdgcn_readlane(s, (K));                                  \
            unsigned short uu = *(const unsigned short*)(h8 + (size_t)se * 128 + 2 * lane); \
            f32x2v v = __builtin_amdgcn_cvt_pk_f32_fp8((int)uu, false);                  \
            den += we;                                                                   \
            nx = fmaf(we, v[0], nx);                                                     \
            ny = fmaf(we, v[1], ny);                                                     \
        }
        A1_STEP(0) A1_STEP(1) A1_STEP(2) A1_STEP(3)
        A1_STEP(4) A1_STEP(5) A1_STEP(6) A1_STEP(7)
#undef A1_STEP
    }
    float inv = 1.f / (den + 1e-16f);
    float2 b = ((const float2*)bias)[lane];
    f16x2 r;
    r[0] = (f16)fmaxf(fmaf(nx, inv, b.x), 0.f);
    r[1] = (f16)fmaxf(fmaf(ny, inv, b.y), 0.f);
    ((f16x2*)out)[(size_t)d * 64 + lane] = r;
}

// ---------------------------------------------------------------------------
// Layer 2 fused aggregation + bias + log_softmax. Weight AND row idx via
// readlane -> SGPR (uniform) -> scalar fma operand + saddr gather.
// ---------------------------------------------------------------------------
__global__ __launch_bounds__(256) void aggr2_k(const int* __restrict__ rp,
                                               const int* __restrict__ csrc,
                                               const float* __restrict__ a_s,
                                               const float* __restrict__ a_d,
                                               const unsigned char* __restrict__ h8,
                                               const float* __restrict__ bias,
                                               float* __restrict__ out) {
    int lane = threadIdx.x & 63;
    int d = blockIdx.x * 4 + (threadIdx.x >> 6);
    if (d >= N_NODES) return;

    float ed = a_d[d];
    float e0 = a_s[d] + ed;
    e0 = e0 > 0.f ? e0 : NEG_SLOPE * e0;
    float w0 = __expf(e0);
    float v0 = __builtin_amdgcn_cvt_f32_fp8((int)h8[(size_t)d * 64 + lane], 0);
    float den = w0, num = w0 * v0;

    int beg = rp[d], end = rp[d + 1];
    for (int cbeg = beg; cbeg < end; cbeg += 8) {
        int e = cbeg + (lane & 7);
        int s = 0;
        float w = 0.f;
        if (e < end) {
            s = csrc[e];
            float es = a_s[s] + ed;
            es = es > 0.f ? es : NEG_SLOPE * es;
            w = __expf(es);
        }
#define A2_STEP(K)                                                                 \
        {                                                                          \
            float we = __int_as_float(                                             \
                __builtin_amdgcn_readlane(__float_as_int(w), (K)));                \
            int se = __builtin_amdgcn_readlane(s, (K));                            \
            float v = __builtin_amdgcn_cvt_f32_fp8(                                \
                (int)h8[(size_t)se * 64 + lane], 0);                               \
            den += we;                                                             \
            num = fmaf(we, v, num);                                                \
        }
        A2_STEP(0) A2_STEP(1) A2_STEP(2) A2_STEP(3)
        A2_STEP(4) A2_STEP(5) A2_STEP(6) A2_STEP(7)
#undef A2_STEP
    }
    float z = num / (den + 1e-16f) + bias[lane];

    float m = z;
#pragma unroll
    for (int o = 32; o > 0; o >>= 1) m = fmaxf(m, __shfl_xor(m, o, 64));
    float p = __expf(z - m);
    float ssum = p;
#pragma unroll
    for (int o = 32; o > 0; o >>= 1) ssum += __shfl_xor(ssum, o, 64);
    out[(size_t)d * 64 + lane] = z - m - logf(ssum);
}

// ---------------------------------------------------------------------------
extern "C" void kernel_launch(void* const* d_in, const int* in_sizes, int n_in,
                              void* d_out, int out_size, void* d_ws, size_t ws_size,
                              hipStream_t stream) {
    const float* x   = (const float*)d_in[0];
    const void*  ei  = d_in[1];
    const float* W1  = (const float*)d_in[2];
    const float* as1 = (const float*)d_in[3];
    const float* ad1 = (const float*)d_in[4];
    const float* b1  = (const float*)d_in[5];
    const float* W2  = (const float*)d_in[6];
    const float* as2 = (const float*)d_in[7];
    const float* ad2 = (const float*)d_in[8];
    const float* b2  = (const float*)d_in[9];
    float* out = (float*)d_out;

    // workspace layout
    f16*   h1   = (f16*)d_ws;                             // N*128 f16 (reused as h2)
    f16*   out1 = h1 + (size_t)N_NODES * 128;             // N*128 f16
    unsigned char* h8 = (unsigned char*)(out1 + (size_t)N_NODES * 128);  // N*128 B
    f16*   w1f  = (f16*)(h8 + (size_t)N_NODES * 128);     // 16384 f16
    f16*   w2f  = w1f + 16384;                            // 8192 f16
    float* a_s  = (float*)(w2f + 8192);                   // N*8 f32
    float* a_d  = a_s + (size_t)N_NODES * 8;              // N*8 f32
    int*   rp   = (int*)(a_d + (size_t)N_NODES * 8);      // N+1 (+pad to 64)
    int*   bh   = rp + (N_NODES + 64);                    // NBUCK*B1 = 200192
    int*   bsum = bh + NSCAN;                             // 256
    int*   csrc = bsum + 256;                             // E
    int2*  be   = (int2*)(csrc + N_EDGES);                // E int2 (8B aligned)
    f16*   h2   = h1;

    // --- CSR build: LDS-atomic bucket counting sort (no global atomics) ---
    bhist_k<<<B1, 256, 0, stream>>>(ei, bh);
    scan1_k<<<SCAN_NB, SCAN_BLK, 0, stream>>>(bh, bh, bsum, NSCAN);
    scan2_k<<<1, 256, 0, stream>>>(bsum, SCAN_NB);
    scan3_k<<<(NSCAN + 255) / 256, 256, 0, stream>>>(bh, bsum, NSCAN);
    bscatter_k<<<B1, 256, 0, stream>>>(ei, bh, be);
    bcsr_k<<<NBUCK, 256, 0, stream>>>(bh, be, rp, csrc);

    // --- weight fragment prep ---
    cvt_wfrag_k<8><<<(4 * 8 * 512 + 255) / 256, 256, 0, stream>>>(W1, w1f);
    cvt_wfrag_k<4><<<(4 * 4 * 512 + 255) / 256, 256, 0, stream>>>(W2, w2f);

    // --- layer 1 ---
    gemm_mfma<8, float><<<(N_NODES + 63) / 64, 256, 0, stream>>>(x, w1f, h1, N_NODES);
    att_scores<8, 16><<<(N_NODES * 8 + 255) / 256, 256, 0, stream>>>(h1, as1, ad1, a_s, a_d, h8, N_NODES);
    aggr1_k<<<(N_NODES + 3) / 4, 256, 0, stream>>>(rp, csrc, a_s, a_d, h8, b1, out1);

    // --- layer 2 (fused bias + log_softmax) ---
    gemm_mfma<4, f16><<<(N_NODES + 63) / 64, 256, 0, stream>>>(out1, w2f, h2, N_NODES);
    att_scores<1, 64><<<(N_NODES + 255) / 256, 256, 0, stream>>>(h2, as2, ad2, a_s, a_d, h8, N_NODES);
    aggr2_k<<<(N_NODES + 3) / 4, 256, 0, stream>>>(rp, csrc, a_s, a_d, h8, b2, out);
}